// Round 6
// baseline (678.441 us; speedup 1.0000x reference)
//
#include <hip/hip_runtime.h>
#include <hip/hip_bf16.h>

// Problem constants
#define D_MODEL 1024
#define D_INNER 4096
#define D_STATE 16
#define D_CONV 4
#define DT_RANK 64
#define BATCH 2
#define SEQLEN 2048
#define MROWS (BATCH * SEQLEN)          // 4096
#define NPROJ (DT_RANK + 2 * D_STATE)   // 96
#define PST 128                         // proj row stride (padded, fp32)
#define NC 32                           // scan chunks
#define TC (SEQLEN / NC)                // 64 steps per chunk
#define KSPLIT 8                        // split-K for proj gemm

typedef unsigned short u16;
typedef unsigned int u32;
typedef __attribute__((ext_vector_type(8))) short short8;
typedef __attribute__((ext_vector_type(4))) float floatx4;

__device__ __forceinline__ float bf2f(u16 u) {
    union { u32 i; float f; } v; v.i = ((u32)u) << 16; return v.f;
}
__device__ __forceinline__ u16 f2bf(float f) {
    union { float f; u32 i; } v; v.f = f;
    u32 x = v.i;
    u32 r = x + 0x7fffu + ((x >> 16) & 1u);   // round to nearest even
    return (u16)(r >> 16);
}
__device__ __forceinline__ float softplusf(float x) {
    return x > 0.f ? x + log1pf(expf(-x)) : log1pf(expf(x));
}
// async global->LDS 16B DMA (dest = wave-uniform base + lane*16)
__device__ __forceinline__ void async_cp16(const u16* g, u16* l) {
    __builtin_amdgcn_global_load_lds((const __attribute__((address_space(1))) void*)g,
                                     (__attribute__((address_space(3))) void*)l, 16, 0, 0);
}

// ---------------------------------------------------------------------------
// D0: detect input dtype (bf16 vs fp32) from exponent-field statistics.
__global__ __launch_bounds__(256) void detect_dtype(const u16* __restrict__ x, int* __restrict__ flag) {
    __shared__ int cnt;
    if (threadIdx.x == 0) cnt = 0;
    __syncthreads();
    int local = 0;
    for (int k = 0; k < 16; k++) {
        int e = threadIdx.x * 8192 + k * 512;
        u16 v = x[2 * e];
        int ex = (v >> 7) & 0xFF;
        if (ex >= 0x68 && ex <= 0x8F) local++;
    }
    atomicAdd(&cnt, local);
    __syncthreads();
    if (threadIdx.x == 0) *flag = (cnt >= 2458) ? 1 : 0;
}

// ---------------------------------------------------------------------------
__global__ __launch_bounds__(256) void ingest16(const void* __restrict__ src, u16* __restrict__ dst,
                                                int n, const int* __restrict__ flag) {
    int i = blockIdx.x * 256 + threadIdx.x;
    if (i >= n) return;
    if (*flag) dst[i] = ((const u16*)src)[i];
    else       dst[i] = f2bf(((const float*)src)[i]);
}

// ---------------------------------------------------------------------------
// Transpose-ingest: W [K][N] (dual dtype) -> WT [N][K] bf16.
__global__ __launch_bounds__(256) void transpose_w(const void* __restrict__ W, u16* __restrict__ WT,
                                                   int K, int N, const int* __restrict__ flag) {
    __shared__ float t[32][33];
    int k0 = blockIdx.y * 32, n0 = blockIdx.x * 32;
    int tid = threadIdx.x;
    int r = tid >> 3, c4 = (tid & 7) * 4;
    int isb = *flag;
    size_t base = (size_t)(k0 + r) * N + n0 + c4;
    float4 v;
    if (isb) { ushort4 u4 = *(const ushort4*)((const u16*)W + base);
               v = make_float4(bf2f(u4.x), bf2f(u4.y), bf2f(u4.z), bf2f(u4.w)); }
    else     { v = *(const float4*)((const float*)W + base); }
    t[c4 + 0][r] = v.x; t[c4 + 1][r] = v.y; t[c4 + 2][r] = v.z; t[c4 + 3][r] = v.w;
    __syncthreads();
    u16* o = WT + (size_t)(n0 + r) * K + k0 + c4;
    o[0] = f2bf(t[r][c4 + 0]);
    o[1] = f2bf(t[r][c4 + 1]);
    o[2] = f2bf(t[r][c4 + 2]);
    o[3] = f2bf(t[r][c4 + 3]);
}

// ---------------------------------------------------------------------------
__global__ __launch_bounds__(256) void prep_A(const void* __restrict__ A_log, float* __restrict__ A,
                                              const int* __restrict__ flag) {
    int i = blockIdx.x * 256 + threadIdx.x;
    if (i >= D_INNER * D_STATE) return;
    float v = (*flag) ? bf2f(((const u16*)A_log)[i]) : ((const float*)A_log)[i];
    A[i] = -expf(v);
}

// ---------------------------------------------------------------------------
// MFMA GEMM: C[M][N] = A[M][K] x Bt[N][K]^T.  bf16 in, fp32 accum.
// 128x128 tile, BK=32, 4 waves each computing 64x64 via 4x4 of 16x16x32.
// mode 0: bf16 store to dst.  mode 1: dual-dtype store per *flag.
__global__ __launch_bounds__(256) void gemm_bt(const u16* __restrict__ A, const u16* __restrict__ Bt,
                                               int K, void* __restrict__ dst, int ldd,
                                               int mode, const int* __restrict__ flag) {
    __shared__ __align__(16) u16 sA[128 * 32];   // [row 128][k 32]
    __shared__ __align__(16) u16 sB[128 * 32];   // [n 128][k 32]
    int tid = threadIdx.x;
    int lane = tid & 63;
    int wave = tid >> 6;
    int wm = (wave >> 1) * 64, wn = (wave & 1) * 64;
    int quad = lane >> 4, l15 = lane & 15;
    int m0 = blockIdx.y * 128, n0 = blockIdx.x * 128;

    floatx4 acc[4][4];
#pragma unroll
    for (int i = 0; i < 4; i++)
#pragma unroll
        for (int j = 0; j < 4; j++) acc[i][j] = (floatx4)0.f;

    const u16* ga0 = A + (size_t)(m0 + (tid >> 2)) * K + (tid & 3) * 8;
    const u16* ga1 = A + (size_t)(m0 + 64 + (tid >> 2)) * K + (tid & 3) * 8;
    const u16* gb0 = Bt + (size_t)(n0 + (tid >> 2)) * K + (tid & 3) * 8;
    const u16* gb1 = Bt + (size_t)(n0 + 64 + (tid >> 2)) * K + (tid & 3) * 8;
    u16* la0 = &sA[tid * 8];
    u16* la1 = &sA[(256 + tid) * 8];
    u16* lb0 = &sB[tid * 8];
    u16* lb1 = &sB[(256 + tid) * 8];

    for (int k0 = 0; k0 < K; k0 += 32) {
        async_cp16(ga0 + k0, la0);
        async_cp16(ga1 + k0, la1);
        async_cp16(gb0 + k0, lb0);
        async_cp16(gb1 + k0, lb1);
        __syncthreads();
        short8 af[4], bf[4];
#pragma unroll
        for (int i = 0; i < 4; i++) {
            af[i] = *(const short8*)&sA[(wm + i * 16 + l15) * 32 + quad * 8];
            bf[i] = *(const short8*)&sB[(wn + i * 16 + l15) * 32 + quad * 8];
        }
#pragma unroll
        for (int i = 0; i < 4; i++)
#pragma unroll
            for (int j = 0; j < 4; j++)
                acc[i][j] = __builtin_amdgcn_mfma_f32_16x16x32_bf16(af[i], bf[j], acc[i][j], 0, 0, 0);
        __syncthreads();
    }

    // C/D layout: col = lane&15, row = quad*4 + reg
    if (mode == 0 || *flag) {
        u16* d = (u16*)dst;
#pragma unroll
        for (int i = 0; i < 4; i++)
#pragma unroll
            for (int j = 0; j < 4; j++)
#pragma unroll
                for (int r = 0; r < 4; r++) {
                    int mm = m0 + wm + i * 16 + quad * 4 + r;
                    int nn = n0 + wn + j * 16 + l15;
                    d[(size_t)mm * ldd + nn] = f2bf(acc[i][j][r]);
                }
    } else {
        float* d = (float*)dst;
#pragma unroll
        for (int i = 0; i < 4; i++)
#pragma unroll
            for (int j = 0; j < 4; j++)
#pragma unroll
                for (int r = 0; r < 4; r++) {
                    int mm = m0 + wm + i * 16 + quad * 4 + r;
                    int nn = n0 + wn + j * 16 + l15;
                    d[(size_t)mm * ldd + nn] = acc[i][j][r];
                }
    }
}

// ---------------------------------------------------------------------------
// K3: proj split-K MFMA.  A = xs [4096][4096], Bt = xpwT [128(pad)][4096].
__global__ __launch_bounds__(256) void gemm_proj(const u16* __restrict__ A, const u16* __restrict__ Bt,
                                                 float* __restrict__ Pp) {
    const int K = D_INNER;
    __shared__ __align__(16) u16 sA[128 * 32];
    __shared__ __align__(16) u16 sB[128 * 32];
    int tid = threadIdx.x;
    int lane = tid & 63;
    int wave = tid >> 6;
    int wm = (wave >> 1) * 64, wn = (wave & 1) * 64;
    int quad = lane >> 4, l15 = lane & 15;
    int m0 = blockIdx.y * 128;
    int kz = blockIdx.x;
    int kbase = kz * (K / KSPLIT);

    floatx4 acc[4][4];
#pragma unroll
    for (int i = 0; i < 4; i++)
#pragma unroll
        for (int j = 0; j < 4; j++) acc[i][j] = (floatx4)0.f;

    const u16* ga0 = A + (size_t)(m0 + (tid >> 2)) * K + (tid & 3) * 8;
    const u16* ga1 = A + (size_t)(m0 + 64 + (tid >> 2)) * K + (tid & 3) * 8;
    const u16* gb0 = Bt + (size_t)(tid >> 2) * K + (tid & 3) * 8;
    const u16* gb1 = Bt + (size_t)(64 + (tid >> 2)) * K + (tid & 3) * 8;
    u16* la0 = &sA[tid * 8];
    u16* la1 = &sA[(256 + tid) * 8];
    u16* lb0 = &sB[tid * 8];
    u16* lb1 = &sB[(256 + tid) * 8];

    for (int k0 = kbase; k0 < kbase + K / KSPLIT; k0 += 32) {
        async_cp16(ga0 + k0, la0);
        async_cp16(ga1 + k0, la1);
        async_cp16(gb0 + k0, lb0);
        async_cp16(gb1 + k0, lb1);
        __syncthreads();
        short8 af[4], bf[4];
#pragma unroll
        for (int i = 0; i < 4; i++) {
            af[i] = *(const short8*)&sA[(wm + i * 16 + l15) * 32 + quad * 8];
            bf[i] = *(const short8*)&sB[(wn + i * 16 + l15) * 32 + quad * 8];
        }
#pragma unroll
        for (int i = 0; i < 4; i++)
#pragma unroll
            for (int j = 0; j < 4; j++)
                acc[i][j] = __builtin_amdgcn_mfma_f32_16x16x32_bf16(af[i], bf[j], acc[i][j], 0, 0, 0);
        __syncthreads();
    }

    float* d = Pp + (size_t)kz * MROWS * PST;
#pragma unroll
    for (int i = 0; i < 4; i++)
#pragma unroll
        for (int j = 0; j < 4; j++)
#pragma unroll
            for (int r = 0; r < 4; r++) {
                int mm = m0 + wm + i * 16 + quad * 4 + r;
                int nn = wn + j * 16 + l15;
                d[(size_t)mm * PST + nn] = acc[i][j][r];
            }
}

// ---------------------------------------------------------------------------
// reduce split-K partials -> proj fp32 [4096][PST]; also emit proj_lo bf16
// [4096][64] (dt-GEMM A operand).
__global__ __launch_bounds__(256) void reduce_proj(const float* __restrict__ Pp, float* __restrict__ proj,
                                                   u16* __restrict__ proj_lo) {
    int i = blockIdx.x * 256 + threadIdx.x;    // < MROWS*PST
    float s = 0.f;
#pragma unroll
    for (int z = 0; z < KSPLIT; z++) s += Pp[(size_t)z * MROWS * PST + i];
    proj[i] = s;
    int col = i & (PST - 1);
    if (col < DT_RANK) proj_lo[(size_t)(i >> 7) * DT_RANK + col] = f2bf(s);
}

// ---------------------------------------------------------------------------
// K4: dt = softplus(proj_lo @ dtwT^T + b) via MFMA.  M=4096, N=4096, K=64.
// A = proj_lo [4096][64] bf16, Bt = dtwT [4096][64] bf16. Epilogue fuses
// bias + softplus, stores bf16 dt[(b,t)][d].
__global__ __launch_bounds__(256) void gemm_dt(const u16* __restrict__ A, const u16* __restrict__ Bt,
                                               const u16* __restrict__ dtb, u16* __restrict__ dt) {
    const int K = DT_RANK;   // 64
    __shared__ __align__(16) u16 sA[128 * 32];
    __shared__ __align__(16) u16 sB[128 * 32];
    int tid = threadIdx.x;
    int lane = tid & 63;
    int wave = tid >> 6;
    int wm = (wave >> 1) * 64, wn = (wave & 1) * 64;
    int quad = lane >> 4, l15 = lane & 15;
    int m0 = blockIdx.y * 128, n0 = blockIdx.x * 128;

    floatx4 acc[4][4];
#pragma unroll
    for (int i = 0; i < 4; i++)
#pragma unroll
        for (int j = 0; j < 4; j++) acc[i][j] = (floatx4)0.f;

    const u16* ga0 = A + (size_t)(m0 + (tid >> 2)) * K + (tid & 3) * 8;
    const u16* ga1 = A + (size_t)(m0 + 64 + (tid >> 2)) * K + (tid & 3) * 8;
    const u16* gb0 = Bt + (size_t)(n0 + (tid >> 2)) * K + (tid & 3) * 8;
    const u16* gb1 = Bt + (size_t)(n0 + 64 + (tid >> 2)) * K + (tid & 3) * 8;
    u16* la0 = &sA[tid * 8];
    u16* la1 = &sA[(256 + tid) * 8];
    u16* lb0 = &sB[tid * 8];
    u16* lb1 = &sB[(256 + tid) * 8];

    for (int k0 = 0; k0 < K; k0 += 32) {
        async_cp16(ga0 + k0, la0);
        async_cp16(ga1 + k0, la1);
        async_cp16(gb0 + k0, lb0);
        async_cp16(gb1 + k0, lb1);
        __syncthreads();
        short8 af[4], bf[4];
#pragma unroll
        for (int i = 0; i < 4; i++) {
            af[i] = *(const short8*)&sA[(wm + i * 16 + l15) * 32 + quad * 8];
            bf[i] = *(const short8*)&sB[(wn + i * 16 + l15) * 32 + quad * 8];
        }
#pragma unroll
        for (int i = 0; i < 4; i++)
#pragma unroll
            for (int j = 0; j < 4; j++)
                acc[i][j] = __builtin_amdgcn_mfma_f32_16x16x32_bf16(af[i], bf[j], acc[i][j], 0, 0, 0);
        __syncthreads();
    }

#pragma unroll
    for (int j = 0; j < 4; j++) {
        int nn = n0 + wn + j * 16 + l15;
        float b = bf2f(dtb[nn]);
#pragma unroll
        for (int i = 0; i < 4; i++)
#pragma unroll
            for (int r = 0; r < 4; r++) {
                int mm = m0 + wm + i * 16 + quad * 4 + r;
                dt[(size_t)mm * D_INNER + nn] = f2bf(softplusf(acc[i][j][r] + b));
            }
    }
}

// ---------------------------------------------------------------------------
// K2: causal depthwise conv1d + silu (bf16 in/out)
__global__ __launch_bounds__(256) void conv_silu(const u16* __restrict__ xc, const u16* __restrict__ cw,
                                                 const u16* __restrict__ cb, u16* __restrict__ xs) {
    int idx = blockIdx.x * 256 + threadIdx.x;
    int d = idx & (D_INNER - 1);
    int t = (idx >> 12) & (SEQLEN - 1);
    int b = idx >> 23;
    float w0 = bf2f(cw[d * 4 + 0]), w1 = bf2f(cw[d * 4 + 1]);
    float w2 = bf2f(cw[d * 4 + 2]), w3 = bf2f(cw[d * 4 + 3]);
    float acc = bf2f(cb[d]);
    size_t base = (size_t)b * SEQLEN * D_INNER + d;
    if (t >= 3) acc += bf2f(xc[base + (size_t)(t - 3) * D_INNER]) * w0;
    if (t >= 2) acc += bf2f(xc[base + (size_t)(t - 2) * D_INNER]) * w1;
    if (t >= 1) acc += bf2f(xc[base + (size_t)(t - 1) * D_INNER]) * w2;
    acc += bf2f(xc[base + (size_t)t * D_INNER]) * w3;
    float s = acc / (1.f + expf(-acc));
    xs[idx] = f2bf(s);
}

// ---------------------------------------------------------------------------
// K5a: chunked scan phase 1 — per (b,d,chunk) thread, 16 states in registers.
__global__ __launch_bounds__(256) void scan_phase1(const float* __restrict__ proj, const u16* __restrict__ dt,
                                                   const float* __restrict__ A, const u16* __restrict__ xs,
                                                   float* __restrict__ hloc, float* __restrict__ Ssum) {
    __shared__ float Bsh[TC][16];
    int d = blockIdx.x * 256 + threadIdx.x;
    int c = blockIdx.y, b = blockIdx.z;
    int t0 = c * TC;
    {
        int i = threadIdx.x >> 2;
        int q = threadIdx.x & 3;
        const float* src = proj + ((size_t)b * SEQLEN + t0 + i) * PST + DT_RANK + q * 4;
        *(float4*)&Bsh[i][q * 4] = *(const float4*)src;
    }
    __syncthreads();
    float Areg[16];
#pragma unroll
    for (int n = 0; n < 16; n++) Areg[n] = A[d * 16 + n];
    float h[16];
#pragma unroll
    for (int n = 0; n < 16; n++) h[n] = 0.f;
    float S = 0.f;
    size_t base = ((size_t)b * SEQLEN + t0) * D_INNER + d;
    for (int t = 0; t < TC; t++) {
        size_t idx = base + (size_t)t * D_INNER;
        float dtv = bf2f(dt[idx]);
        float u = bf2f(xs[idx]);
        S += dtv;
        float du = dtv * u;
#pragma unroll
        for (int n = 0; n < 16; n++) {
            h[n] = h[n] * __expf(dtv * Areg[n]) + du * Bsh[t][n];
        }
    }
    float* hp = &hloc[(((size_t)b * NC + c) * D_INNER + d) * 16];
#pragma unroll
    for (int n = 0; n < 16; n += 4)
        *(float4*)&hp[n] = make_float4(h[n], h[n + 1], h[n + 2], h[n + 3]);
    Ssum[((size_t)b * NC + c) * D_INNER + d] = S;
}

// ---------------------------------------------------------------------------
// K5b: combine chunks serially (in place: hloc becomes h_init per chunk).
__global__ __launch_bounds__(256) void scan_phase2(const float* __restrict__ A, const float* __restrict__ Ssum,
                                                   float* __restrict__ hloc) {
    int tid = blockIdx.x * 256 + threadIdx.x;
    int n = tid & 15;
    int d = (tid >> 4) & (D_INNER - 1);
    int b = tid >> 16;
    float An = A[d * 16 + n];
    float h = 0.f;
    for (int c = 0; c < NC; c++) {
        size_t idx = (((size_t)b * NC + c) * D_INNER + d) * 16 + n;
        float hl = hloc[idx];
        float S = Ssum[((size_t)b * NC + c) * D_INNER + d];
        hloc[idx] = h;
        h = hl + h * __expf(An * S);
    }
}

// ---------------------------------------------------------------------------
// K5c: phase 3 — rerun chunk with h_init, compute y, D-residual, silu(z) gate.
__global__ __launch_bounds__(256) void scan_phase3(const float* __restrict__ proj, const u16* __restrict__ dt,
                                                   const float* __restrict__ A, const u16* __restrict__ D16,
                                                   const float* __restrict__ hinit, const u16* __restrict__ z16,
                                                   u16* __restrict__ xs) {
    __shared__ float BC[TC][32];
    int d = blockIdx.x * 256 + threadIdx.x;
    int c = blockIdx.y, b = blockIdx.z;
    int t0 = c * TC;
    {
        int i = threadIdx.x >> 2;
        int q = threadIdx.x & 3;
        const float* src = proj + ((size_t)b * SEQLEN + t0 + i) * PST + DT_RANK + q * 8;
        *(float4*)&BC[i][q * 8 + 0] = *(const float4*)(src + 0);
        *(float4*)&BC[i][q * 8 + 4] = *(const float4*)(src + 4);
    }
    __syncthreads();
    float Areg[16];
#pragma unroll
    for (int n = 0; n < 16; n++) Areg[n] = A[d * 16 + n];
    float h[16];
    {
        const float* hp = &hinit[(((size_t)b * NC + c) * D_INNER + d) * 16];
#pragma unroll
        for (int n = 0; n < 16; n += 4) {
            float4 v = *(const float4*)&hp[n];
            h[n] = v.x; h[n + 1] = v.y; h[n + 2] = v.z; h[n + 3] = v.w;
        }
    }
    float Dd = bf2f(D16[d]);
    size_t base = ((size_t)b * SEQLEN + t0) * D_INNER + d;
    for (int t = 0; t < TC; t++) {
        size_t idx = base + (size_t)t * D_INNER;
        float dtv = bf2f(dt[idx]);
        float u = bf2f(xs[idx]);
        float zv = bf2f(z16[idx]);
        float du = dtv * u;
        float y = 0.f;
#pragma unroll
        for (int n = 0; n < 16; n++) {
            h[n] = h[n] * __expf(dtv * Areg[n]) + du * BC[t][n];
            y += h[n] * BC[t][16 + n];
        }
        float gate = zv / (1.f + __expf(-zv));
        xs[idx] = f2bf((y + u * Dd) * gate);
    }
}

// ---------------------------------------------------------------------------
extern "C" void kernel_launch(void* const* d_in, const int* in_sizes, int n_in,
                              void* d_out, int out_size, void* d_ws, size_t ws_size,
                              hipStream_t stream) {
    const void* x          = d_in[0];
    const void* in_proj_w  = d_in[1];
    const void* conv_w     = d_in[2];
    const void* conv_b     = d_in[3];
    const void* x_proj_w   = d_in[4];
    const void* dt_proj_w  = d_in[5];
    const void* dt_proj_b  = d_in[6];
    const void* A_log      = d_in[7];
    const void* Dvec       = d_in[8];
    const void* out_proj_w = d_in[9];

    char* w = (char*)d_ws;
    const size_t MB = 1024 * 1024;
    const size_t KB = 1024;
    int*   flag    = (int*)(w + 0);
    float* Aws     = (float*)(w + 1 * KB);          // 256 KB
    float* proj    = (float*)(w + 1 * MB);          // 2 MB fp32 [4096][PST=128]
    u16*   cw16    = (u16*)(w + 3 * MB);            // 32 KB
    u16*   cb16    = (u16*)(w + 3 * MB + 64 * KB);  // 8 KB
    u16*   dtb16   = (u16*)(w + 3 * MB + 128 * KB); // 8 KB
    u16*   D16     = (u16*)(w + 3 * MB + 192 * KB); // 8 KB
    u16*   proj_lo = (u16*)(w + 3 * MB + 512 * KB); // 512 KB bf16 [4096][64]
    u16*   dtwT    = (u16*)(w + 4 * MB);            // 512 KB bf16 [4096][64]
    u16*   buf1    = (u16*)(w + 5 * MB);            // 32 MB: xc then z
    u16*   xs      = (u16*)(w + 37 * MB);           // 32 MB: xs then gated y
    u16*   dt16    = (u16*)(w + 69 * MB);           // 32 MB (overlays x16/ipwT after they die)
    u16*   x16     = (u16*)(w + 69 * MB);           // 8.4 MB
    u16*   ipwT    = (u16*)(w + 78 * MB);           // 16.8 MB: in_proj_w^T [8192][1024]
    float* hloc    = (float*)(w + 101 * MB);        // 16 MB
    float* Ssum    = (float*)(w + 117 * MB);        // 1 MB
    u16*   opwT    = (u16*)(w + 118 * MB);          // 8.4 MB: out_proj_w^T [1024][4096]
    u16*   xpwT    = (u16*)(w + 127 * MB);          // 1 MB: x_proj_w^T [96(pad128)][4096]
    float* Pp      = (float*)(w + 128 * MB);        // 16 MB: split-K partials [8][4096][128]
    // total 144 MB (<150 MB proven available)

    detect_dtype<<<dim3(1), dim3(256), 0, stream>>>((const u16*)x, flag);
    ingest16<<<dim3(64), dim3(256), 0, stream>>>(conv_w, cw16, D_INNER * D_CONV, flag);
    ingest16<<<dim3(16), dim3(256), 0, stream>>>(conv_b, cb16, D_INNER, flag);
    ingest16<<<dim3(16), dim3(256), 0, stream>>>(dt_proj_b, dtb16, D_INNER, flag);
    ingest16<<<dim3(16), dim3(256), 0, stream>>>(Dvec, D16, D_INNER, flag);
    prep_A<<<dim3(256), dim3(256), 0, stream>>>(A_log, Aws, flag);
    ingest16<<<dim3(MROWS * D_MODEL / 256), dim3(256), 0, stream>>>(x, x16, MROWS * D_MODEL, flag);
    transpose_w<<<dim3(2 * D_INNER / 32, D_MODEL / 32), dim3(256), 0, stream>>>(in_proj_w, ipwT, D_MODEL, 2 * D_INNER, flag);
    transpose_w<<<dim3(D_MODEL / 32, D_INNER / 32), dim3(256), 0, stream>>>(out_proj_w, opwT, D_INNER, D_MODEL, flag);
    transpose_w<<<dim3(NPROJ / 32, D_INNER / 32), dim3(256), 0, stream>>>(x_proj_w, xpwT, D_INNER, NPROJ, flag);
    transpose_w<<<dim3(D_INNER / 32, DT_RANK / 32), dim3(256), 0, stream>>>(dt_proj_w, dtwT, DT_RANK, D_INNER, flag);

    // K1a: xc = x @ Win[:, :4096]
    gemm_bt<<<dim3(D_INNER / 128, MROWS / 128), dim3(256), 0, stream>>>(
        x16, ipwT, D_MODEL, buf1, D_INNER, 0, flag);
    // K2: conv + silu -> xs
    conv_silu<<<dim3(MROWS * D_INNER / 256), dim3(256), 0, stream>>>(buf1, cw16, cb16, xs);
    // K1b: z = x @ Win[:, 4096:]  (overwrites xc, dead after conv)
    gemm_bt<<<dim3(D_INNER / 128, MROWS / 128), dim3(256), 0, stream>>>(
        x16, ipwT + (size_t)D_INNER * D_MODEL, D_MODEL, buf1, D_INNER, 0, flag);
    // K3: proj via split-K MFMA + reduce (also emits proj_lo bf16)
    gemm_proj<<<dim3(KSPLIT, MROWS / 128), dim3(256), 0, stream>>>(xs, xpwT, Pp);
    reduce_proj<<<dim3(MROWS * PST / 256), dim3(256), 0, stream>>>(Pp, proj, proj_lo);
    // K4: dt via MFMA with fused bias+softplus (writes dt16, overlaying dead x16/ipwT)
    gemm_dt<<<dim3(D_INNER / 128, MROWS / 128), dim3(256), 0, stream>>>(proj_lo, dtwT, dtb16, dt16);
    // K5: chunked scan
    scan_phase1<<<dim3(D_INNER / 256, NC, BATCH), dim3(256), 0, stream>>>(proj, dt16, Aws, xs, hloc, Ssum);
    scan_phase2<<<dim3(BATCH * D_INNER * D_STATE / 256), dim3(256), 0, stream>>>(Aws, Ssum, hloc);
    scan_phase3<<<dim3(D_INNER / 256, NC, BATCH), dim3(256), 0, stream>>>(proj, dt16, Aws, D16, hloc, buf1, xs);
    // K6: out = y @ out_proj_w
    gemm_bt<<<dim3(D_MODEL / 128, MROWS / 128), dim3(256), 0, stream>>>(
        xs, opwT, D_INNER, d_out, D_MODEL, 1, flag);
}

// Round 7
// 596.119 us; speedup vs baseline: 1.1381x; 1.1381x over previous
//
#include <hip/hip_runtime.h>
#include <hip/hip_bf16.h>

// Problem constants
#define D_MODEL 1024
#define D_INNER 4096
#define D_STATE 16
#define D_CONV 4
#define DT_RANK 64
#define BATCH 2
#define SEQLEN 2048
#define MROWS (BATCH * SEQLEN)          // 4096
#define NPROJ (DT_RANK + 2 * D_STATE)   // 96
#define PST 128                         // proj row stride (padded, fp32)
#define NC 32                           // scan chunks
#define TC (SEQLEN / NC)                // 64 steps per chunk
#define KSPLIT 8                        // split-K for proj gemm

typedef unsigned short u16;
typedef unsigned int u32;
typedef __attribute__((ext_vector_type(8))) short short8;
typedef __attribute__((ext_vector_type(4))) float floatx4;

__device__ __forceinline__ float bf2f(u16 u) {
    union { u32 i; float f; } v; v.i = ((u32)u) << 16; return v.f;
}
__device__ __forceinline__ u16 f2bf(float f) {
    union { float f; u32 i; } v; v.f = f;
    u32 x = v.i;
    u32 r = x + 0x7fffu + ((x >> 16) & 1u);   // round to nearest even
    return (u16)(r >> 16);
}
__device__ __forceinline__ float softplusf(float x) {
    return x > 0.f ? x + log1pf(expf(-x)) : log1pf(expf(x));
}
// fast softplus: hardware exp/log; |err| << bf16 ulp for all finite x
__device__ __forceinline__ float softplus_fast(float x) {
    float l = __logf(1.f + __expf(-fabsf(x)));
    return x > 0.f ? x + l : l;
}
// async global->LDS 16B DMA (dest = wave-uniform base + lane*16)
__device__ __forceinline__ void async_cp16(const u16* g, u16* l) {
    __builtin_amdgcn_global_load_lds((const __attribute__((address_space(1))) void*)g,
                                     (__attribute__((address_space(3))) void*)l, 16, 0, 0);
}

// ---------------------------------------------------------------------------
// D0: detect input dtype (bf16 vs fp32) from exponent-field statistics.
__global__ __launch_bounds__(256) void detect_dtype(const u16* __restrict__ x, int* __restrict__ flag) {
    __shared__ int cnt;
    if (threadIdx.x == 0) cnt = 0;
    __syncthreads();
    int local = 0;
    for (int k = 0; k < 16; k++) {
        int e = threadIdx.x * 8192 + k * 512;
        u16 v = x[2 * e];
        int ex = (v >> 7) & 0xFF;
        if (ex >= 0x68 && ex <= 0x8F) local++;
    }
    atomicAdd(&cnt, local);
    __syncthreads();
    if (threadIdx.x == 0) *flag = (cnt >= 2458) ? 1 : 0;
}

// ---------------------------------------------------------------------------
__global__ __launch_bounds__(256) void ingest16(const void* __restrict__ src, u16* __restrict__ dst,
                                                int n, const int* __restrict__ flag) {
    int i = blockIdx.x * 256 + threadIdx.x;
    if (i >= n) return;
    if (*flag) dst[i] = ((const u16*)src)[i];
    else       dst[i] = f2bf(((const float*)src)[i]);
}

// ---------------------------------------------------------------------------
// Transpose-ingest: W [K][N] (dual dtype) -> WT [N][K] bf16.
__global__ __launch_bounds__(256) void transpose_w(const void* __restrict__ W, u16* __restrict__ WT,
                                                   int K, int N, const int* __restrict__ flag) {
    __shared__ float t[32][33];
    int k0 = blockIdx.y * 32, n0 = blockIdx.x * 32;
    int tid = threadIdx.x;
    int r = tid >> 3, c4 = (tid & 7) * 4;
    int isb = *flag;
    size_t base = (size_t)(k0 + r) * N + n0 + c4;
    float4 v;
    if (isb) { ushort4 u4 = *(const ushort4*)((const u16*)W + base);
               v = make_float4(bf2f(u4.x), bf2f(u4.y), bf2f(u4.z), bf2f(u4.w)); }
    else     { v = *(const float4*)((const float*)W + base); }
    t[c4 + 0][r] = v.x; t[c4 + 1][r] = v.y; t[c4 + 2][r] = v.z; t[c4 + 3][r] = v.w;
    __syncthreads();
    u16* o = WT + (size_t)(n0 + r) * K + k0 + c4;
    o[0] = f2bf(t[r][c4 + 0]);
    o[1] = f2bf(t[r][c4 + 1]);
    o[2] = f2bf(t[r][c4 + 2]);
    o[3] = f2bf(t[r][c4 + 3]);
}

// ---------------------------------------------------------------------------
__global__ __launch_bounds__(256) void prep_A(const void* __restrict__ A_log, float* __restrict__ A,
                                              const int* __restrict__ flag) {
    int i = blockIdx.x * 256 + threadIdx.x;
    if (i >= D_INNER * D_STATE) return;
    float v = (*flag) ? bf2f(((const u16*)A_log)[i]) : ((const float*)A_log)[i];
    A[i] = -expf(v);
}

// ---------------------------------------------------------------------------
// MFMA GEMM: C[M][N] = A[M][K] x Bt[N][K]^T.  bf16 in, fp32 accum.
// 128x128 tile, BK=32, 4 waves each computing 64x64 via 4x4 of 16x16x32.
// mode 0: bf16 store.  mode 1: dual-dtype store per *flag.
// sw: 0 -> m0 from blockIdx.y (grid x=n); 1 -> m0 from blockIdx.x (grid x=m,
//     better per-XCD L2 working set when n-dim is small, e.g. K6).
__global__ __launch_bounds__(256) void gemm_bt(const u16* __restrict__ A, const u16* __restrict__ Bt,
                                               int K, void* __restrict__ dst, int ldd,
                                               int mode, int sw, const int* __restrict__ flag) {
    __shared__ __align__(16) u16 sA[128 * 32];   // [row 128][k 32]
    __shared__ __align__(16) u16 sB[128 * 32];   // [n 128][k 32]
    int tid = threadIdx.x;
    int lane = tid & 63;
    int wave = tid >> 6;
    int wm = (wave >> 1) * 64, wn = (wave & 1) * 64;
    int quad = lane >> 4, l15 = lane & 15;
    int m0 = (sw ? blockIdx.x : blockIdx.y) * 128;
    int n0 = (sw ? blockIdx.y : blockIdx.x) * 128;

    floatx4 acc[4][4];
#pragma unroll
    for (int i = 0; i < 4; i++)
#pragma unroll
        for (int j = 0; j < 4; j++) acc[i][j] = (floatx4)0.f;

    const u16* ga0 = A + (size_t)(m0 + (tid >> 2)) * K + (tid & 3) * 8;
    const u16* ga1 = A + (size_t)(m0 + 64 + (tid >> 2)) * K + (tid & 3) * 8;
    const u16* gb0 = Bt + (size_t)(n0 + (tid >> 2)) * K + (tid & 3) * 8;
    const u16* gb1 = Bt + (size_t)(n0 + 64 + (tid >> 2)) * K + (tid & 3) * 8;
    u16* la0 = &sA[tid * 8];
    u16* la1 = &sA[(256 + tid) * 8];
    u16* lb0 = &sB[tid * 8];
    u16* lb1 = &sB[(256 + tid) * 8];

    for (int k0 = 0; k0 < K; k0 += 32) {
        async_cp16(ga0 + k0, la0);
        async_cp16(ga1 + k0, la1);
        async_cp16(gb0 + k0, lb0);
        async_cp16(gb1 + k0, lb1);
        __syncthreads();
        short8 af[4], bf[4];
#pragma unroll
        for (int i = 0; i < 4; i++) {
            af[i] = *(const short8*)&sA[(wm + i * 16 + l15) * 32 + quad * 8];
            bf[i] = *(const short8*)&sB[(wn + i * 16 + l15) * 32 + quad * 8];
        }
#pragma unroll
        for (int i = 0; i < 4; i++)
#pragma unroll
            for (int j = 0; j < 4; j++)
                acc[i][j] = __builtin_amdgcn_mfma_f32_16x16x32_bf16(af[i], bf[j], acc[i][j], 0, 0, 0);
        __syncthreads();
    }

    // C/D layout: col = lane&15, row = quad*4 + reg
    if (mode == 0 || *flag) {
        u16* d = (u16*)dst;
#pragma unroll
        for (int i = 0; i < 4; i++)
#pragma unroll
            for (int j = 0; j < 4; j++)
#pragma unroll
                for (int r = 0; r < 4; r++) {
                    int mm = m0 + wm + i * 16 + quad * 4 + r;
                    int nn = n0 + wn + j * 16 + l15;
                    d[(size_t)mm * ldd + nn] = f2bf(acc[i][j][r]);
                }
    } else {
        float* d = (float*)dst;
#pragma unroll
        for (int i = 0; i < 4; i++)
#pragma unroll
            for (int j = 0; j < 4; j++)
#pragma unroll
                for (int r = 0; r < 4; r++) {
                    int mm = m0 + wm + i * 16 + quad * 4 + r;
                    int nn = n0 + wn + j * 16 + l15;
                    d[(size_t)mm * ldd + nn] = acc[i][j][r];
                }
    }
}

// ---------------------------------------------------------------------------
// K3: proj split-K MFMA.  A = xs [4096][4096], Bt = xpwT [128(pad)][4096].
__global__ __launch_bounds__(256) void gemm_proj(const u16* __restrict__ A, const u16* __restrict__ Bt,
                                                 float* __restrict__ Pp) {
    const int K = D_INNER;
    __shared__ __align__(16) u16 sA[128 * 32];
    __shared__ __align__(16) u16 sB[128 * 32];
    int tid = threadIdx.x;
    int lane = tid & 63;
    int wave = tid >> 6;
    int wm = (wave >> 1) * 64, wn = (wave & 1) * 64;
    int quad = lane >> 4, l15 = lane & 15;
    int m0 = blockIdx.y * 128;
    int kz = blockIdx.x;
    int kbase = kz * (K / KSPLIT);

    floatx4 acc[4][4];
#pragma unroll
    for (int i = 0; i < 4; i++)
#pragma unroll
        for (int j = 0; j < 4; j++) acc[i][j] = (floatx4)0.f;

    const u16* ga0 = A + (size_t)(m0 + (tid >> 2)) * K + (tid & 3) * 8;
    const u16* ga1 = A + (size_t)(m0 + 64 + (tid >> 2)) * K + (tid & 3) * 8;
    const u16* gb0 = Bt + (size_t)(tid >> 2) * K + (tid & 3) * 8;
    const u16* gb1 = Bt + (size_t)(64 + (tid >> 2)) * K + (tid & 3) * 8;
    u16* la0 = &sA[tid * 8];
    u16* la1 = &sA[(256 + tid) * 8];
    u16* lb0 = &sB[tid * 8];
    u16* lb1 = &sB[(256 + tid) * 8];

    for (int k0 = kbase; k0 < kbase + K / KSPLIT; k0 += 32) {
        async_cp16(ga0 + k0, la0);
        async_cp16(ga1 + k0, la1);
        async_cp16(gb0 + k0, lb0);
        async_cp16(gb1 + k0, lb1);
        __syncthreads();
        short8 af[4], bf[4];
#pragma unroll
        for (int i = 0; i < 4; i++) {
            af[i] = *(const short8*)&sA[(wm + i * 16 + l15) * 32 + quad * 8];
            bf[i] = *(const short8*)&sB[(wn + i * 16 + l15) * 32 + quad * 8];
        }
#pragma unroll
        for (int i = 0; i < 4; i++)
#pragma unroll
            for (int j = 0; j < 4; j++)
                acc[i][j] = __builtin_amdgcn_mfma_f32_16x16x32_bf16(af[i], bf[j], acc[i][j], 0, 0, 0);
        __syncthreads();
    }

    float* d = Pp + (size_t)kz * MROWS * PST;
#pragma unroll
    for (int i = 0; i < 4; i++)
#pragma unroll
        for (int j = 0; j < 4; j++)
#pragma unroll
            for (int r = 0; r < 4; r++) {
                int mm = m0 + wm + i * 16 + quad * 4 + r;
                int nn = wn + j * 16 + l15;
                d[(size_t)mm * PST + nn] = acc[i][j][r];
            }
}

// ---------------------------------------------------------------------------
// reduce split-K partials -> proj fp32 [4096][PST]; also emit proj_lo bf16
// [4096][64] (dt-GEMM A operand).
__global__ __launch_bounds__(256) void reduce_proj(const float* __restrict__ Pp, float* __restrict__ proj,
                                                   u16* __restrict__ proj_lo) {
    int i = blockIdx.x * 256 + threadIdx.x;    // < MROWS*PST
    float s = 0.f;
#pragma unroll
    for (int z = 0; z < KSPLIT; z++) s += Pp[(size_t)z * MROWS * PST + i];
    proj[i] = s;
    int col = i & (PST - 1);
    if (col < DT_RANK) proj_lo[(size_t)(i >> 7) * DT_RANK + col] = f2bf(s);
}

// ---------------------------------------------------------------------------
// K4: dt = softplus(proj_lo @ dtwT^T + b) via MFMA.  M=4096, N=4096, K=64.
// Epilogue: fast softplus + LDS bounce (stride-132 pad) -> coalesced 16B stores.
__global__ __launch_bounds__(256) void gemm_dt(const u16* __restrict__ A, const u16* __restrict__ Bt,
                                               const u16* __restrict__ dtb, u16* __restrict__ dt) {
    const int K = DT_RANK;   // 64
    __shared__ __align__(16) u16 smem[64 * 132];   // 16.9 KB; k-loop uses first 16 KB
    u16* sA = smem;
    u16* sB = smem + 128 * 32;
    int tid = threadIdx.x;
    int lane = tid & 63;
    int wave = tid >> 6;
    int wm = (wave >> 1) * 64, wn = (wave & 1) * 64;
    int quad = lane >> 4, l15 = lane & 15;
    int m0 = blockIdx.y * 128, n0 = blockIdx.x * 128;

    floatx4 acc[4][4];
#pragma unroll
    for (int i = 0; i < 4; i++)
#pragma unroll
        for (int j = 0; j < 4; j++) acc[i][j] = (floatx4)0.f;

    const u16* ga0 = A + (size_t)(m0 + (tid >> 2)) * K + (tid & 3) * 8;
    const u16* ga1 = A + (size_t)(m0 + 64 + (tid >> 2)) * K + (tid & 3) * 8;
    const u16* gb0 = Bt + (size_t)(n0 + (tid >> 2)) * K + (tid & 3) * 8;
    const u16* gb1 = Bt + (size_t)(n0 + 64 + (tid >> 2)) * K + (tid & 3) * 8;
    u16* la0 = &sA[tid * 8];
    u16* la1 = &sA[(256 + tid) * 8];
    u16* lb0 = &sB[tid * 8];
    u16* lb1 = &sB[(256 + tid) * 8];

    for (int k0 = 0; k0 < K; k0 += 32) {
        async_cp16(ga0 + k0, la0);
        async_cp16(ga1 + k0, la1);
        async_cp16(gb0 + k0, lb0);
        async_cp16(gb1 + k0, lb1);
        __syncthreads();
        short8 af[4], bf[4];
#pragma unroll
        for (int i = 0; i < 4; i++) {
            af[i] = *(const short8*)&sA[(wm + i * 16 + l15) * 32 + quad * 8];
            bf[i] = *(const short8*)&sB[(wn + i * 16 + l15) * 32 + quad * 8];
        }
#pragma unroll
        for (int i = 0; i < 4; i++)
#pragma unroll
            for (int j = 0; j < 4; j++)
                acc[i][j] = __builtin_amdgcn_mfma_f32_16x16x32_bf16(af[i], bf[j], acc[i][j], 0, 0, 0);
        __syncthreads();
    }

    // Epilogue in 2 halves of 64 rows: owning waves (wm==h*64) apply
    // bias+softplus and stage to LDS; all threads then do coalesced stores.
#pragma unroll
    for (int h = 0; h < 2; h++) {
        __syncthreads();
        if (wm == h * 64) {
#pragma unroll
            for (int j = 0; j < 4; j++) {
                int col = wn + j * 16 + l15;
                float b = bf2f(dtb[n0 + col]);
#pragma unroll
                for (int i = 0; i < 4; i++)
#pragma unroll
                    for (int r = 0; r < 4; r++) {
                        int row = i * 16 + quad * 4 + r;   // 0..63 within half
                        smem[row * 132 + col] = f2bf(softplus_fast(acc[i][j][r] + b));
                    }
            }
        }
        __syncthreads();
#pragma unroll
        for (int p = 0; p < 4; p++) {
            int row = p * 16 + (tid >> 4);
            int chunk = tid & 15;
            uint4 v = *(const uint4*)&smem[row * 132 + chunk * 8];
            *(uint4*)&dt[(size_t)(m0 + h * 64 + row) * D_INNER + n0 + chunk * 8] = v;
        }
    }
}

// ---------------------------------------------------------------------------
// K2: causal depthwise conv1d + silu (bf16 in/out)
__global__ __launch_bounds__(256) void conv_silu(const u16* __restrict__ xc, const u16* __restrict__ cw,
                                                 const u16* __restrict__ cb, u16* __restrict__ xs) {
    int idx = blockIdx.x * 256 + threadIdx.x;
    int d = idx & (D_INNER - 1);
    int t = (idx >> 12) & (SEQLEN - 1);
    int b = idx >> 23;
    float w0 = bf2f(cw[d * 4 + 0]), w1 = bf2f(cw[d * 4 + 1]);
    float w2 = bf2f(cw[d * 4 + 2]), w3 = bf2f(cw[d * 4 + 3]);
    float acc = bf2f(cb[d]);
    size_t base = (size_t)b * SEQLEN * D_INNER + d;
    if (t >= 3) acc += bf2f(xc[base + (size_t)(t - 3) * D_INNER]) * w0;
    if (t >= 2) acc += bf2f(xc[base + (size_t)(t - 2) * D_INNER]) * w1;
    if (t >= 1) acc += bf2f(xc[base + (size_t)(t - 1) * D_INNER]) * w2;
    acc += bf2f(xc[base + (size_t)t * D_INNER]) * w3;
    float s = acc / (1.f + expf(-acc));
    xs[idx] = f2bf(s);
}

// ---------------------------------------------------------------------------
// K5a: chunked scan phase 1 — per (b,d,chunk) thread, 16 states in registers.
__global__ __launch_bounds__(256) void scan_phase1(const float* __restrict__ proj, const u16* __restrict__ dt,
                                                   const float* __restrict__ A, const u16* __restrict__ xs,
                                                   float* __restrict__ hloc, float* __restrict__ Ssum) {
    __shared__ float Bsh[TC][16];
    int d = blockIdx.x * 256 + threadIdx.x;
    int c = blockIdx.y, b = blockIdx.z;
    int t0 = c * TC;
    {
        int i = threadIdx.x >> 2;
        int q = threadIdx.x & 3;
        const float* src = proj + ((size_t)b * SEQLEN + t0 + i) * PST + DT_RANK + q * 4;
        *(float4*)&Bsh[i][q * 4] = *(const float4*)src;
    }
    __syncthreads();
    float Areg[16];
#pragma unroll
    for (int n = 0; n < 16; n++) Areg[n] = A[d * 16 + n];
    float h[16];
#pragma unroll
    for (int n = 0; n < 16; n++) h[n] = 0.f;
    float S = 0.f;
    size_t base = ((size_t)b * SEQLEN + t0) * D_INNER + d;
    for (int t = 0; t < TC; t++) {
        size_t idx = base + (size_t)t * D_INNER;
        float dtv = bf2f(dt[idx]);
        float u = bf2f(xs[idx]);
        S += dtv;
        float du = dtv * u;
#pragma unroll
        for (int n = 0; n < 16; n++) {
            h[n] = h[n] * __expf(dtv * Areg[n]) + du * Bsh[t][n];
        }
    }
    float* hp = &hloc[(((size_t)b * NC + c) * D_INNER + d) * 16];
#pragma unroll
    for (int n = 0; n < 16; n += 4)
        *(float4*)&hp[n] = make_float4(h[n], h[n + 1], h[n + 2], h[n + 3]);
    Ssum[((size_t)b * NC + c) * D_INNER + d] = S;
}

// ---------------------------------------------------------------------------
// K5b: combine chunks serially (in place: hloc becomes h_init per chunk).
__global__ __launch_bounds__(256) void scan_phase2(const float* __restrict__ A, const float* __restrict__ Ssum,
                                                   float* __restrict__ hloc) {
    int tid = blockIdx.x * 256 + threadIdx.x;
    int n = tid & 15;
    int d = (tid >> 4) & (D_INNER - 1);
    int b = tid >> 16;
    float An = A[d * 16 + n];
    float h = 0.f;
    for (int c = 0; c < NC; c++) {
        size_t idx = (((size_t)b * NC + c) * D_INNER + d) * 16 + n;
        float hl = hloc[idx];
        float S = Ssum[((size_t)b * NC + c) * D_INNER + d];
        hloc[idx] = h;
        h = hl + h * __expf(An * S);
    }
}

// ---------------------------------------------------------------------------
// K5c: phase 3 — rerun chunk with h_init, compute y, D-residual, silu(z) gate.
__global__ __launch_bounds__(256) void scan_phase3(const float* __restrict__ proj, const u16* __restrict__ dt,
                                                   const float* __restrict__ A, const u16* __restrict__ D16,
                                                   const float* __restrict__ hinit, const u16* __restrict__ z16,
                                                   u16* __restrict__ xs) {
    __shared__ float BC[TC][32];
    int d = blockIdx.x * 256 + threadIdx.x;
    int c = blockIdx.y, b = blockIdx.z;
    int t0 = c * TC;
    {
        int i = threadIdx.x >> 2;
        int q = threadIdx.x & 3;
        const float* src = proj + ((size_t)b * SEQLEN + t0 + i) * PST + DT_RANK + q * 8;
        *(float4*)&BC[i][q * 8 + 0] = *(const float4*)(src + 0);
        *(float4*)&BC[i][q * 8 + 4] = *(const float4*)(src + 4);
    }
    __syncthreads();
    float Areg[16];
#pragma unroll
    for (int n = 0; n < 16; n++) Areg[n] = A[d * 16 + n];
    float h[16];
    {
        const float* hp = &hinit[(((size_t)b * NC + c) * D_INNER + d) * 16];
#pragma unroll
        for (int n = 0; n < 16; n += 4) {
            float4 v = *(const float4*)&hp[n];
            h[n] = v.x; h[n + 1] = v.y; h[n + 2] = v.z; h[n + 3] = v.w;
        }
    }
    float Dd = bf2f(D16[d]);
    size_t base = ((size_t)b * SEQLEN + t0) * D_INNER + d;
    for (int t = 0; t < TC; t++) {
        size_t idx = base + (size_t)t * D_INNER;
        float dtv = bf2f(dt[idx]);
        float u = bf2f(xs[idx]);
        float zv = bf2f(z16[idx]);
        float du = dtv * u;
        float y = 0.f;
#pragma unroll
        for (int n = 0; n < 16; n++) {
            h[n] = h[n] * __expf(dtv * Areg[n]) + du * BC[t][n];
            y += h[n] * BC[t][16 + n];
        }
        float gate = zv / (1.f + __expf(-zv));
        xs[idx] = f2bf((y + u * Dd) * gate);
    }
}

// ---------------------------------------------------------------------------
extern "C" void kernel_launch(void* const* d_in, const int* in_sizes, int n_in,
                              void* d_out, int out_size, void* d_ws, size_t ws_size,
                              hipStream_t stream) {
    const void* x          = d_in[0];
    const void* in_proj_w  = d_in[1];
    const void* conv_w     = d_in[2];
    const void* conv_b     = d_in[3];
    const void* x_proj_w   = d_in[4];
    const void* dt_proj_w  = d_in[5];
    const void* dt_proj_b  = d_in[6];
    const void* A_log      = d_in[7];
    const void* Dvec       = d_in[8];
    const void* out_proj_w = d_in[9];

    char* w = (char*)d_ws;
    const size_t MB = 1024 * 1024;
    const size_t KB = 1024;
    int*   flag    = (int*)(w + 0);
    float* Aws     = (float*)(w + 1 * KB);          // 256 KB
    float* proj    = (float*)(w + 1 * MB);          // 2 MB fp32 [4096][PST=128]
    u16*   cw16    = (u16*)(w + 3 * MB);            // 32 KB
    u16*   cb16    = (u16*)(w + 3 * MB + 64 * KB);  // 8 KB
    u16*   dtb16   = (u16*)(w + 3 * MB + 128 * KB); // 8 KB
    u16*   D16     = (u16*)(w + 3 * MB + 192 * KB); // 8 KB
    u16*   proj_lo = (u16*)(w + 3 * MB + 512 * KB); // 512 KB bf16 [4096][64]
    u16*   dtwT    = (u16*)(w + 4 * MB);            // 512 KB bf16 [4096][64]
    u16*   buf1    = (u16*)(w + 5 * MB);            // 32 MB: xc then z
    u16*   xs      = (u16*)(w + 37 * MB);           // 32 MB: xs then gated y
    u16*   dt16    = (u16*)(w + 69 * MB);           // 32 MB (overlays x16/ipwT after they die)
    u16*   x16     = (u16*)(w + 69 * MB);           // 8.4 MB
    u16*   ipwT    = (u16*)(w + 78 * MB);           // 16.8 MB: in_proj_w^T [8192][1024]
    float* hloc    = (float*)(w + 101 * MB);        // 16 MB
    float* Ssum    = (float*)(w + 117 * MB);        // 1 MB
    u16*   opwT    = (u16*)(w + 118 * MB);          // 8.4 MB: out_proj_w^T [1024][4096]
    u16*   xpwT    = (u16*)(w + 127 * MB);          // 1 MB: x_proj_w^T [96(pad128)][4096]
    float* Pp      = (float*)(w + 128 * MB);        // 16 MB: split-K partials [8][4096][128]
    // total 144 MB (<150 MB proven available)

    detect_dtype<<<dim3(1), dim3(256), 0, stream>>>((const u16*)x, flag);
    ingest16<<<dim3(64), dim3(256), 0, stream>>>(conv_w, cw16, D_INNER * D_CONV, flag);
    ingest16<<<dim3(16), dim3(256), 0, stream>>>(conv_b, cb16, D_INNER, flag);
    ingest16<<<dim3(16), dim3(256), 0, stream>>>(dt_proj_b, dtb16, D_INNER, flag);
    ingest16<<<dim3(16), dim3(256), 0, stream>>>(Dvec, D16, D_INNER, flag);
    prep_A<<<dim3(256), dim3(256), 0, stream>>>(A_log, Aws, flag);
    ingest16<<<dim3(MROWS * D_MODEL / 256), dim3(256), 0, stream>>>(x, x16, MROWS * D_MODEL, flag);
    transpose_w<<<dim3(2 * D_INNER / 32, D_MODEL / 32), dim3(256), 0, stream>>>(in_proj_w, ipwT, D_MODEL, 2 * D_INNER, flag);
    transpose_w<<<dim3(D_MODEL / 32, D_INNER / 32), dim3(256), 0, stream>>>(out_proj_w, opwT, D_INNER, D_MODEL, flag);
    transpose_w<<<dim3(NPROJ / 32, D_INNER / 32), dim3(256), 0, stream>>>(x_proj_w, xpwT, D_INNER, NPROJ, flag);
    transpose_w<<<dim3(D_INNER / 32, DT_RANK / 32), dim3(256), 0, stream>>>(dt_proj_w, dtwT, DT_RANK, D_INNER, flag);

    // K1a: xc = x @ Win[:, :4096]
    gemm_bt<<<dim3(D_INNER / 128, MROWS / 128), dim3(256), 0, stream>>>(
        x16, ipwT, D_MODEL, buf1, D_INNER, 0, 0, flag);
    // K2: conv + silu -> xs
    conv_silu<<<dim3(MROWS * D_INNER / 256), dim3(256), 0, stream>>>(buf1, cw16, cb16, xs);
    // K1b: z = x @ Win[:, 4096:]  (overwrites xc, dead after conv)
    gemm_bt<<<dim3(D_INNER / 128, MROWS / 128), dim3(256), 0, stream>>>(
        x16, ipwT + (size_t)D_INNER * D_MODEL, D_MODEL, buf1, D_INNER, 0, 0, flag);
    // K3: proj via split-K MFMA + reduce (also emits proj_lo bf16)
    gemm_proj<<<dim3(KSPLIT, MROWS / 128), dim3(256), 0, stream>>>(xs, xpwT, Pp);
    reduce_proj<<<dim3(MROWS * PST / 256), dim3(256), 0, stream>>>(Pp, proj, proj_lo);
    // K4: dt via MFMA with fused bias+fast-softplus, coalesced epilogue
    gemm_dt<<<dim3(D_INNER / 128, MROWS / 128), dim3(256), 0, stream>>>(proj_lo, dtwT, dtb16, dt16);
    // K5: chunked scan
    scan_phase1<<<dim3(D_INNER / 256, NC, BATCH), dim3(256), 0, stream>>>(proj, dt16, Aws, xs, hloc, Ssum);
    scan_phase2<<<dim3(BATCH * D_INNER * D_STATE / 256), dim3(256), 0, stream>>>(Aws, Ssum, hloc);
    scan_phase3<<<dim3(D_INNER / 256, NC, BATCH), dim3(256), 0, stream>>>(proj, dt16, Aws, D16, hloc, buf1, xs);
    // K6: out = y @ out_proj_w   (sw=1: grid x=m for per-XCD L2 locality)
    gemm_bt<<<dim3(MROWS / 128, D_MODEL / 128), dim3(256), 0, stream>>>(
        xs, opwT, D_INNER, d_out, D_MODEL, 1, 1, flag);
}

// Round 8
// 566.231 us; speedup vs baseline: 1.1982x; 1.0528x over previous
//
#include <hip/hip_runtime.h>
#include <hip/hip_bf16.h>

// Problem constants
#define D_MODEL 1024
#define D_INNER 4096
#define D_STATE 16
#define D_CONV 4
#define DT_RANK 64
#define BATCH 2
#define SEQLEN 2048
#define MROWS (BATCH * SEQLEN)          // 4096
#define NPROJ (DT_RANK + 2 * D_STATE)   // 96
#define PST 128                         // proj row stride (padded, fp32)
#define NC 32                           // scan chunks
#define TC (SEQLEN / NC)                // 64 steps per chunk
#define KSPLIT 8                        // split-K for proj gemm

typedef unsigned short u16;
typedef unsigned int u32;
typedef __attribute__((ext_vector_type(8))) short short8;
typedef __attribute__((ext_vector_type(4))) float floatx4;

__device__ __forceinline__ float bf2f(u16 u) {
    union { u32 i; float f; } v; v.i = ((u32)u) << 16; return v.f;
}
__device__ __forceinline__ u16 f2bf(float f) {
    union { float f; u32 i; } v; v.f = f;
    u32 x = v.i;
    u32 r = x + 0x7fffu + ((x >> 16) & 1u);   // round to nearest even
    return (u16)(r >> 16);
}
__device__ __forceinline__ float softplusf(float x) {
    return x > 0.f ? x + log1pf(expf(-x)) : log1pf(expf(x));
}
// fast softplus: hardware exp/log; |err| << bf16 ulp for all finite x
__device__ __forceinline__ float softplus_fast(float x) {
    float l = __logf(1.f + __expf(-fabsf(x)));
    return x > 0.f ? x + l : l;
}
// async global->LDS 16B DMA (dest = wave-uniform base + lane*16)
__device__ __forceinline__ void async_cp16(const u16* g, u16* l) {
    __builtin_amdgcn_global_load_lds((const __attribute__((address_space(1))) void*)g,
                                     (__attribute__((address_space(3))) void*)l, 16, 0, 0);
}

// ---------------------------------------------------------------------------
// D0: detect input dtype (bf16 vs fp32) from exponent-field statistics.
__global__ __launch_bounds__(256) void detect_dtype(const u16* __restrict__ x, int* __restrict__ flag) {
    __shared__ int cnt;
    if (threadIdx.x == 0) cnt = 0;
    __syncthreads();
    int local = 0;
    for (int k = 0; k < 16; k++) {
        int e = threadIdx.x * 8192 + k * 512;
        u16 v = x[2 * e];
        int ex = (v >> 7) & 0xFF;
        if (ex >= 0x68 && ex <= 0x8F) local++;
    }
    atomicAdd(&cnt, local);
    __syncthreads();
    if (threadIdx.x == 0) *flag = (cnt >= 2458) ? 1 : 0;
}

// ---------------------------------------------------------------------------
__global__ __launch_bounds__(256) void ingest16(const void* __restrict__ src, u16* __restrict__ dst,
                                                int n, const int* __restrict__ flag) {
    int i = blockIdx.x * 256 + threadIdx.x;
    if (i >= n) return;
    if (*flag) dst[i] = ((const u16*)src)[i];
    else       dst[i] = f2bf(((const float*)src)[i]);
}

// ---------------------------------------------------------------------------
// Transpose-ingest: W [K][N] (dual dtype) -> WT [N][K] bf16.
__global__ __launch_bounds__(256) void transpose_w(const void* __restrict__ W, u16* __restrict__ WT,
                                                   int K, int N, const int* __restrict__ flag) {
    __shared__ float t[32][33];
    int k0 = blockIdx.y * 32, n0 = blockIdx.x * 32;
    int tid = threadIdx.x;
    int r = tid >> 3, c4 = (tid & 7) * 4;
    int isb = *flag;
    size_t base = (size_t)(k0 + r) * N + n0 + c4;
    float4 v;
    if (isb) { ushort4 u4 = *(const ushort4*)((const u16*)W + base);
               v = make_float4(bf2f(u4.x), bf2f(u4.y), bf2f(u4.z), bf2f(u4.w)); }
    else     { v = *(const float4*)((const float*)W + base); }
    t[c4 + 0][r] = v.x; t[c4 + 1][r] = v.y; t[c4 + 2][r] = v.z; t[c4 + 3][r] = v.w;
    __syncthreads();
    u16* o = WT + (size_t)(n0 + r) * K + k0 + c4;
    o[0] = f2bf(t[r][c4 + 0]);
    o[1] = f2bf(t[r][c4 + 1]);
    o[2] = f2bf(t[r][c4 + 2]);
    o[3] = f2bf(t[r][c4 + 3]);
}

// ---------------------------------------------------------------------------
__global__ __launch_bounds__(256) void prep_A(const void* __restrict__ A_log, float* __restrict__ A,
                                              const int* __restrict__ flag) {
    int i = blockIdx.x * 256 + threadIdx.x;
    if (i >= D_INNER * D_STATE) return;
    float v = (*flag) ? bf2f(((const u16*)A_log)[i]) : ((const float*)A_log)[i];
    A[i] = -expf(v);
}

// ---------------------------------------------------------------------------
// K1 merged: xz = x @ in_proj_w, N=8192.  Blocks with n0 < 4096 write xc,
// others write z (each ld D_INNER).  128x128 tile, BK=32, m97 structure.
__global__ __launch_bounds__(256) void gemm_in2(const u16* __restrict__ A, const u16* __restrict__ Bt,
                                                u16* __restrict__ xc, u16* __restrict__ z) {
    const int K = D_MODEL;
    __shared__ __align__(16) u16 sA[128 * 32];
    __shared__ __align__(16) u16 sB[128 * 32];
    int tid = threadIdx.x;
    int lane = tid & 63;
    int wave = tid >> 6;
    int wm = (wave >> 1) * 64, wn = (wave & 1) * 64;
    int quad = lane >> 4, l15 = lane & 15;
    int m0 = blockIdx.y * 128, n0 = blockIdx.x * 128;

    floatx4 acc[4][4];
#pragma unroll
    for (int i = 0; i < 4; i++)
#pragma unroll
        for (int j = 0; j < 4; j++) acc[i][j] = (floatx4)0.f;

    const u16* ga0 = A + (size_t)(m0 + (tid >> 2)) * K + (tid & 3) * 8;
    const u16* ga1 = A + (size_t)(m0 + 64 + (tid >> 2)) * K + (tid & 3) * 8;
    const u16* gb0 = Bt + (size_t)(n0 + (tid >> 2)) * K + (tid & 3) * 8;
    const u16* gb1 = Bt + (size_t)(n0 + 64 + (tid >> 2)) * K + (tid & 3) * 8;
    u16* la0 = &sA[tid * 8];
    u16* la1 = &sA[(256 + tid) * 8];
    u16* lb0 = &sB[tid * 8];
    u16* lb1 = &sB[(256 + tid) * 8];

    for (int k0 = 0; k0 < K; k0 += 32) {
        async_cp16(ga0 + k0, la0);
        async_cp16(ga1 + k0, la1);
        async_cp16(gb0 + k0, lb0);
        async_cp16(gb1 + k0, lb1);
        __syncthreads();
        short8 af[4], bf[4];
#pragma unroll
        for (int i = 0; i < 4; i++) {
            af[i] = *(const short8*)&sA[(wm + i * 16 + l15) * 32 + quad * 8];
            bf[i] = *(const short8*)&sB[(wn + i * 16 + l15) * 32 + quad * 8];
        }
#pragma unroll
        for (int i = 0; i < 4; i++)
#pragma unroll
            for (int j = 0; j < 4; j++)
                acc[i][j] = __builtin_amdgcn_mfma_f32_16x16x32_bf16(af[i], bf[j], acc[i][j], 0, 0, 0);
        __syncthreads();
    }

    u16* d = (n0 < D_INNER) ? xc : z;
    int nb = (n0 < D_INNER) ? n0 : n0 - D_INNER;
#pragma unroll
    for (int i = 0; i < 4; i++)
#pragma unroll
        for (int j = 0; j < 4; j++)
#pragma unroll
            for (int r = 0; r < 4; r++) {
                int mm = m0 + wm + i * 16 + quad * 4 + r;
                int nn = nb + wn + j * 16 + l15;
                d[(size_t)mm * D_INNER + nn] = f2bf(acc[i][j][r]);
            }
}

// ---------------------------------------------------------------------------
// MFMA GEMM: C[M][N] = A[M][K] x Bt[N][K]^T.  bf16 in, fp32 accum.
// mode 0: bf16 store.  mode 1: dual-dtype store per *flag.
// sw: 1 -> grid x=m (per-XCD L2 locality when n-dim small, e.g. K6).
__global__ __launch_bounds__(256) void gemm_bt(const u16* __restrict__ A, const u16* __restrict__ Bt,
                                               int K, void* __restrict__ dst, int ldd,
                                               int mode, int sw, const int* __restrict__ flag) {
    __shared__ __align__(16) u16 sA[128 * 32];
    __shared__ __align__(16) u16 sB[128 * 32];
    int tid = threadIdx.x;
    int lane = tid & 63;
    int wave = tid >> 6;
    int wm = (wave >> 1) * 64, wn = (wave & 1) * 64;
    int quad = lane >> 4, l15 = lane & 15;
    int m0 = (sw ? blockIdx.x : blockIdx.y) * 128;
    int n0 = (sw ? blockIdx.y : blockIdx.x) * 128;

    floatx4 acc[4][4];
#pragma unroll
    for (int i = 0; i < 4; i++)
#pragma unroll
        for (int j = 0; j < 4; j++) acc[i][j] = (floatx4)0.f;

    const u16* ga0 = A + (size_t)(m0 + (tid >> 2)) * K + (tid & 3) * 8;
    const u16* ga1 = A + (size_t)(m0 + 64 + (tid >> 2)) * K + (tid & 3) * 8;
    const u16* gb0 = Bt + (size_t)(n0 + (tid >> 2)) * K + (tid & 3) * 8;
    const u16* gb1 = Bt + (size_t)(n0 + 64 + (tid >> 2)) * K + (tid & 3) * 8;
    u16* la0 = &sA[tid * 8];
    u16* la1 = &sA[(256 + tid) * 8];
    u16* lb0 = &sB[tid * 8];
    u16* lb1 = &sB[(256 + tid) * 8];

    for (int k0 = 0; k0 < K; k0 += 32) {
        async_cp16(ga0 + k0, la0);
        async_cp16(ga1 + k0, la1);
        async_cp16(gb0 + k0, lb0);
        async_cp16(gb1 + k0, lb1);
        __syncthreads();
        short8 af[4], bf[4];
#pragma unroll
        for (int i = 0; i < 4; i++) {
            af[i] = *(const short8*)&sA[(wm + i * 16 + l15) * 32 + quad * 8];
            bf[i] = *(const short8*)&sB[(wn + i * 16 + l15) * 32 + quad * 8];
        }
#pragma unroll
        for (int i = 0; i < 4; i++)
#pragma unroll
            for (int j = 0; j < 4; j++)
                acc[i][j] = __builtin_amdgcn_mfma_f32_16x16x32_bf16(af[i], bf[j], acc[i][j], 0, 0, 0);
        __syncthreads();
    }

    // C/D layout: col = lane&15, row = quad*4 + reg
    if (mode == 0 || *flag) {
        u16* d = (u16*)dst;
#pragma unroll
        for (int i = 0; i < 4; i++)
#pragma unroll
            for (int j = 0; j < 4; j++)
#pragma unroll
                for (int r = 0; r < 4; r++) {
                    int mm = m0 + wm + i * 16 + quad * 4 + r;
                    int nn = n0 + wn + j * 16 + l15;
                    d[(size_t)mm * ldd + nn] = f2bf(acc[i][j][r]);
                }
    } else {
        float* d = (float*)dst;
#pragma unroll
        for (int i = 0; i < 4; i++)
#pragma unroll
            for (int j = 0; j < 4; j++)
#pragma unroll
                for (int r = 0; r < 4; r++) {
                    int mm = m0 + wm + i * 16 + quad * 4 + r;
                    int nn = n0 + wn + j * 16 + l15;
                    d[(size_t)mm * ldd + nn] = acc[i][j][r];
                }
    }
}

// ---------------------------------------------------------------------------
// K3: proj split-K MFMA.  A = xs [4096][4096], Bt = xpwT [128(pad)][4096].
__global__ __launch_bounds__(256) void gemm_proj(const u16* __restrict__ A, const u16* __restrict__ Bt,
                                                 float* __restrict__ Pp) {
    const int K = D_INNER;
    __shared__ __align__(16) u16 sA[128 * 32];
    __shared__ __align__(16) u16 sB[128 * 32];
    int tid = threadIdx.x;
    int lane = tid & 63;
    int wave = tid >> 6;
    int wm = (wave >> 1) * 64, wn = (wave & 1) * 64;
    int quad = lane >> 4, l15 = lane & 15;
    int m0 = blockIdx.y * 128;
    int kz = blockIdx.x;
    int kbase = kz * (K / KSPLIT);

    floatx4 acc[4][4];
#pragma unroll
    for (int i = 0; i < 4; i++)
#pragma unroll
        for (int j = 0; j < 4; j++) acc[i][j] = (floatx4)0.f;

    const u16* ga0 = A + (size_t)(m0 + (tid >> 2)) * K + (tid & 3) * 8;
    const u16* ga1 = A + (size_t)(m0 + 64 + (tid >> 2)) * K + (tid & 3) * 8;
    const u16* gb0 = Bt + (size_t)(tid >> 2) * K + (tid & 3) * 8;
    const u16* gb1 = Bt + (size_t)(64 + (tid >> 2)) * K + (tid & 3) * 8;
    u16* la0 = &sA[tid * 8];
    u16* la1 = &sA[(256 + tid) * 8];
    u16* lb0 = &sB[tid * 8];
    u16* lb1 = &sB[(256 + tid) * 8];

    for (int k0 = kbase; k0 < kbase + K / KSPLIT; k0 += 32) {
        async_cp16(ga0 + k0, la0);
        async_cp16(ga1 + k0, la1);
        async_cp16(gb0 + k0, lb0);
        async_cp16(gb1 + k0, lb1);
        __syncthreads();
        short8 af[4], bf[4];
#pragma unroll
        for (int i = 0; i < 4; i++) {
            af[i] = *(const short8*)&sA[(wm + i * 16 + l15) * 32 + quad * 8];
            bf[i] = *(const short8*)&sB[(wn + i * 16 + l15) * 32 + quad * 8];
        }
#pragma unroll
        for (int i = 0; i < 4; i++)
#pragma unroll
            for (int j = 0; j < 4; j++)
                acc[i][j] = __builtin_amdgcn_mfma_f32_16x16x32_bf16(af[i], bf[j], acc[i][j], 0, 0, 0);
        __syncthreads();
    }

    float* d = Pp + (size_t)kz * MROWS * PST;
#pragma unroll
    for (int i = 0; i < 4; i++)
#pragma unroll
        for (int j = 0; j < 4; j++)
#pragma unroll
            for (int r = 0; r < 4; r++) {
                int mm = m0 + wm + i * 16 + quad * 4 + r;
                int nn = wn + j * 16 + l15;
                d[(size_t)mm * PST + nn] = acc[i][j][r];
            }
}

// ---------------------------------------------------------------------------
// reduce split-K partials -> proj fp32 [4096][PST]; also emit proj_lo bf16.
__global__ __launch_bounds__(256) void reduce_proj(const float* __restrict__ Pp, float* __restrict__ proj,
                                                   u16* __restrict__ proj_lo) {
    int i = blockIdx.x * 256 + threadIdx.x;    // < MROWS*PST
    float s = 0.f;
#pragma unroll
    for (int z = 0; z < KSPLIT; z++) s += Pp[(size_t)z * MROWS * PST + i];
    proj[i] = s;
    int col = i & (PST - 1);
    if (col < DT_RANK) proj_lo[(size_t)(i >> 7) * DT_RANK + col] = f2bf(s);
}

// ---------------------------------------------------------------------------
// K4: dt = softplus(proj_lo @ dtwT^T + b) via MFMA.  M=4096, N=4096, K=64.
// Epilogue: fast softplus + LDS bounce (stride-132 pad) -> coalesced 16B stores.
__global__ __launch_bounds__(256) void gemm_dt(const u16* __restrict__ A, const u16* __restrict__ Bt,
                                               const u16* __restrict__ dtb, u16* __restrict__ dt) {
    const int K = DT_RANK;   // 64
    __shared__ __align__(16) u16 smem[64 * 132];   // 16.9 KB; k-loop uses first 16 KB
    u16* sA = smem;
    u16* sB = smem + 128 * 32;
    int tid = threadIdx.x;
    int lane = tid & 63;
    int wave = tid >> 6;
    int wm = (wave >> 1) * 64, wn = (wave & 1) * 64;
    int quad = lane >> 4, l15 = lane & 15;
    int m0 = blockIdx.y * 128, n0 = blockIdx.x * 128;

    floatx4 acc[4][4];
#pragma unroll
    for (int i = 0; i < 4; i++)
#pragma unroll
        for (int j = 0; j < 4; j++) acc[i][j] = (floatx4)0.f;

    const u16* ga0 = A + (size_t)(m0 + (tid >> 2)) * K + (tid & 3) * 8;
    const u16* ga1 = A + (size_t)(m0 + 64 + (tid >> 2)) * K + (tid & 3) * 8;
    const u16* gb0 = Bt + (size_t)(n0 + (tid >> 2)) * K + (tid & 3) * 8;
    const u16* gb1 = Bt + (size_t)(n0 + 64 + (tid >> 2)) * K + (tid & 3) * 8;
    u16* la0 = &sA[tid * 8];
    u16* la1 = &sA[(256 + tid) * 8];
    u16* lb0 = &sB[tid * 8];
    u16* lb1 = &sB[(256 + tid) * 8];

    for (int k0 = 0; k0 < K; k0 += 32) {
        async_cp16(ga0 + k0, la0);
        async_cp16(ga1 + k0, la1);
        async_cp16(gb0 + k0, lb0);
        async_cp16(gb1 + k0, lb1);
        __syncthreads();
        short8 af[4], bf[4];
#pragma unroll
        for (int i = 0; i < 4; i++) {
            af[i] = *(const short8*)&sA[(wm + i * 16 + l15) * 32 + quad * 8];
            bf[i] = *(const short8*)&sB[(wn + i * 16 + l15) * 32 + quad * 8];
        }
#pragma unroll
        for (int i = 0; i < 4; i++)
#pragma unroll
            for (int j = 0; j < 4; j++)
                acc[i][j] = __builtin_amdgcn_mfma_f32_16x16x32_bf16(af[i], bf[j], acc[i][j], 0, 0, 0);
        __syncthreads();
    }

#pragma unroll
    for (int h = 0; h < 2; h++) {
        __syncthreads();
        if (wm == h * 64) {
#pragma unroll
            for (int j = 0; j < 4; j++) {
                int col = wn + j * 16 + l15;
                float b = bf2f(dtb[n0 + col]);
#pragma unroll
                for (int i = 0; i < 4; i++)
#pragma unroll
                    for (int r = 0; r < 4; r++) {
                        int row = i * 16 + quad * 4 + r;   // 0..63 within half
                        smem[row * 132 + col] = f2bf(softplus_fast(acc[i][j][r] + b));
                    }
            }
        }
        __syncthreads();
#pragma unroll
        for (int p = 0; p < 4; p++) {
            int row = p * 16 + (tid >> 4);
            int chunk = tid & 15;
            uint4 v = *(const uint4*)&smem[row * 132 + chunk * 8];
            *(uint4*)&dt[(size_t)(m0 + h * 64 + row) * D_INNER + n0 + chunk * 8] = v;
        }
    }
}

// ---------------------------------------------------------------------------
// K2: causal depthwise conv1d + silu (bf16 in/out)
__global__ __launch_bounds__(256) void conv_silu(const u16* __restrict__ xc, const u16* __restrict__ cw,
                                                 const u16* __restrict__ cb, u16* __restrict__ xs) {
    int idx = blockIdx.x * 256 + threadIdx.x;
    int d = idx & (D_INNER - 1);
    int t = (idx >> 12) & (SEQLEN - 1);
    int b = idx >> 23;
    float w0 = bf2f(cw[d * 4 + 0]), w1 = bf2f(cw[d * 4 + 1]);
    float w2 = bf2f(cw[d * 4 + 2]), w3 = bf2f(cw[d * 4 + 3]);
    float acc = bf2f(cb[d]);
    size_t base = (size_t)b * SEQLEN * D_INNER + d;
    if (t >= 3) acc += bf2f(xc[base + (size_t)(t - 3) * D_INNER]) * w0;
    if (t >= 2) acc += bf2f(xc[base + (size_t)(t - 2) * D_INNER]) * w1;
    if (t >= 1) acc += bf2f(xc[base + (size_t)(t - 1) * D_INNER]) * w2;
    acc += bf2f(xc[base + (size_t)t * D_INNER]) * w3;
    float s = acc / (1.f + expf(-acc));
    xs[idx] = f2bf(s);
}

// ---------------------------------------------------------------------------
// K5a: chunked scan phase 1 — per (b,d,chunk) thread, 16 states in registers.
__global__ __launch_bounds__(256) void scan_phase1(const float* __restrict__ proj, const u16* __restrict__ dt,
                                                   const float* __restrict__ A, const u16* __restrict__ xs,
                                                   float* __restrict__ hloc, float* __restrict__ Ssum) {
    __shared__ float Bsh[TC][16];
    int d = blockIdx.x * 256 + threadIdx.x;
    int c = blockIdx.y, b = blockIdx.z;
    int t0 = c * TC;
    {
        int i = threadIdx.x >> 2;
        int q = threadIdx.x & 3;
        const float* src = proj + ((size_t)b * SEQLEN + t0 + i) * PST + DT_RANK + q * 4;
        *(float4*)&Bsh[i][q * 4] = *(const float4*)src;
    }
    __syncthreads();
    float Areg[16];
#pragma unroll
    for (int n = 0; n < 16; n++) Areg[n] = A[d * 16 + n];
    float h[16];
#pragma unroll
    for (int n = 0; n < 16; n++) h[n] = 0.f;
    float S = 0.f;
    size_t base = ((size_t)b * SEQLEN + t0) * D_INNER + d;
    for (int t = 0; t < TC; t++) {
        size_t idx = base + (size_t)t * D_INNER;
        float dtv = bf2f(dt[idx]);
        float u = bf2f(xs[idx]);
        S += dtv;
        float du = dtv * u;
#pragma unroll
        for (int n = 0; n < 16; n++) {
            h[n] = h[n] * __expf(dtv * Areg[n]) + du * Bsh[t][n];
        }
    }
    float* hp = &hloc[(((size_t)b * NC + c) * D_INNER + d) * 16];
#pragma unroll
    for (int n = 0; n < 16; n += 4)
        *(float4*)&hp[n] = make_float4(h[n], h[n + 1], h[n + 2], h[n + 3]);
    Ssum[((size_t)b * NC + c) * D_INNER + d] = S;
}

// ---------------------------------------------------------------------------
// K5b: combine chunks serially (in place: hloc becomes h_init per chunk).
__global__ __launch_bounds__(256) void scan_phase2(const float* __restrict__ A, const float* __restrict__ Ssum,
                                                   float* __restrict__ hloc) {
    int tid = blockIdx.x * 256 + threadIdx.x;
    int n = tid & 15;
    int d = (tid >> 4) & (D_INNER - 1);
    int b = tid >> 16;
    float An = A[d * 16 + n];
    float h = 0.f;
    for (int c = 0; c < NC; c++) {
        size_t idx = (((size_t)b * NC + c) * D_INNER + d) * 16 + n;
        float hl = hloc[idx];
        float S = Ssum[((size_t)b * NC + c) * D_INNER + d];
        hloc[idx] = h;
        h = hl + h * __expf(An * S);
    }
}

// ---------------------------------------------------------------------------
// K5c: phase 3 — rerun chunk with h_init, compute y, D-residual, silu(z) gate.
__global__ __launch_bounds__(256) void scan_phase3(const float* __restrict__ proj, const u16* __restrict__ dt,
                                                   const float* __restrict__ A, const u16* __restrict__ D16,
                                                   const float* __restrict__ hinit, const u16* __restrict__ z16,
                                                   u16* __restrict__ xs) {
    __shared__ float BC[TC][32];
    int d = blockIdx.x * 256 + threadIdx.x;
    int c = blockIdx.y, b = blockIdx.z;
    int t0 = c * TC;
    {
        int i = threadIdx.x >> 2;
        int q = threadIdx.x & 3;
        const float* src = proj + ((size_t)b * SEQLEN + t0 + i) * PST + DT_RANK + q * 8;
        *(float4*)&BC[i][q * 8 + 0] = *(const float4*)(src + 0);
        *(float4*)&BC[i][q * 8 + 4] = *(const float4*)(src + 4);
    }
    __syncthreads();
    float Areg[16];
#pragma unroll
    for (int n = 0; n < 16; n++) Areg[n] = A[d * 16 + n];
    float h[16];
    {
        const float* hp = &hinit[(((size_t)b * NC + c) * D_INNER + d) * 16];
#pragma unroll
        for (int n = 0; n < 16; n += 4) {
            float4 v = *(const float4*)&hp[n];
            h[n] = v.x; h[n + 1] = v.y; h[n + 2] = v.z; h[n + 3] = v.w;
        }
    }
    float Dd = bf2f(D16[d]);
    size_t base = ((size_t)b * SEQLEN + t0) * D_INNER + d;
    for (int t = 0; t < TC; t++) {
        size_t idx = base + (size_t)t * D_INNER;
        float dtv = bf2f(dt[idx]);
        float u = bf2f(xs[idx]);
        float zv = bf2f(z16[idx]);
        float du = dtv * u;
        float y = 0.f;
#pragma unroll
        for (int n = 0; n < 16; n++) {
            h[n] = h[n] * __expf(dtv * Areg[n]) + du * BC[t][n];
            y += h[n] * BC[t][16 + n];
        }
        float gate = zv / (1.f + __expf(-zv));
        xs[idx] = f2bf((y + u * Dd) * gate);
    }
}

// ---------------------------------------------------------------------------
extern "C" void kernel_launch(void* const* d_in, const int* in_sizes, int n_in,
                              void* d_out, int out_size, void* d_ws, size_t ws_size,
                              hipStream_t stream) {
    const void* x          = d_in[0];
    const void* in_proj_w  = d_in[1];
    const void* conv_w     = d_in[2];
    const void* conv_b     = d_in[3];
    const void* x_proj_w   = d_in[4];
    const void* dt_proj_w  = d_in[5];
    const void* dt_proj_b  = d_in[6];
    const void* A_log      = d_in[7];
    const void* Dvec       = d_in[8];
    const void* out_proj_w = d_in[9];

    char* w = (char*)d_ws;
    const size_t MB = 1024 * 1024;
    const size_t KB = 1024;
    // Workspace overlay plan (sequential stream ordering guarantees safety):
    //   5-37 MB  : xc (K1 out, dead after conv) -> dt16 (gemm_dt out)
    //  37-69 MB  : z (K1 out, live until scan_phase3)
    //  69-101 MB : xs (conv out) -> gated y (scan_phase3 out)
    // 101-126 MB : x16 + ipwT (dead after K1) -> Pp (dead after reduce)
    //              -> hloc/Ssum (scan)
    // 127-136 MB : opwT, xpwT (live until K6 / gemm_proj)
    int*   flag    = (int*)(w + 0);
    float* Aws     = (float*)(w + 1 * KB);          // 256 KB
    float* proj    = (float*)(w + 1 * MB);          // 2 MB fp32 [4096][PST=128]
    u16*   cw16    = (u16*)(w + 3 * MB);            // 32 KB
    u16*   cb16    = (u16*)(w + 3 * MB + 64 * KB);  // 8 KB
    u16*   dtb16   = (u16*)(w + 3 * MB + 128 * KB); // 8 KB
    u16*   D16     = (u16*)(w + 3 * MB + 192 * KB); // 8 KB
    u16*   proj_lo = (u16*)(w + 3 * MB + 512 * KB); // 512 KB bf16 [4096][64]
    u16*   dtwT    = (u16*)(w + 4 * MB);            // 512 KB bf16 [4096][64]
    u16*   buf1    = (u16*)(w + 5 * MB);            // 32 MB: xc then dt16
    u16*   dt16    = buf1;
    u16*   zbuf    = (u16*)(w + 37 * MB);           // 32 MB: z
    u16*   xs      = (u16*)(w + 69 * MB);           // 32 MB: xs then gated y
    u16*   x16     = (u16*)(w + 101 * MB);          // 8.4 MB  (dead after K1)
    u16*   ipwT    = (u16*)(w + 110 * MB);          // 16.8 MB (dead after K1)
    float* Pp      = (float*)(w + 101 * MB);        // 16 MB (post-K1, dead after reduce)
    float* hloc    = (float*)(w + 101 * MB);        // 16 MB (post-reduce)
    float* Ssum    = (float*)(w + 117 * MB);        // 1 MB  (post-K1)
    u16*   opwT    = (u16*)(w + 127 * MB);          // 8.4 MB: out_proj_w^T [1024][4096]
    u16*   xpwT    = (u16*)(w + 136 * MB);          // 1 MB: x_proj_w^T [96(pad128)][4096]
    // total 137 MB (<150 MB proven available)

    detect_dtype<<<dim3(1), dim3(256), 0, stream>>>((const u16*)x, flag);
    ingest16<<<dim3(64), dim3(256), 0, stream>>>(conv_w, cw16, D_INNER * D_CONV, flag);
    ingest16<<<dim3(16), dim3(256), 0, stream>>>(conv_b, cb16, D_INNER, flag);
    ingest16<<<dim3(16), dim3(256), 0, stream>>>(dt_proj_b, dtb16, D_INNER, flag);
    ingest16<<<dim3(16), dim3(256), 0, stream>>>(Dvec, D16, D_INNER, flag);
    prep_A<<<dim3(256), dim3(256), 0, stream>>>(A_log, Aws, flag);
    ingest16<<<dim3(MROWS * D_MODEL / 256), dim3(256), 0, stream>>>(x, x16, MROWS * D_MODEL, flag);
    transpose_w<<<dim3(2 * D_INNER / 32, D_MODEL / 32), dim3(256), 0, stream>>>(in_proj_w, ipwT, D_MODEL, 2 * D_INNER, flag);
    transpose_w<<<dim3(D_MODEL / 32, D_INNER / 32), dim3(256), 0, stream>>>(out_proj_w, opwT, D_INNER, D_MODEL, flag);
    transpose_w<<<dim3(NPROJ / 32, D_INNER / 32), dim3(256), 0, stream>>>(x_proj_w, xpwT, D_INNER, NPROJ, flag);
    transpose_w<<<dim3(D_INNER / 32, DT_RANK / 32), dim3(256), 0, stream>>>(dt_proj_w, dtwT, DT_RANK, D_INNER, flag);

    // K1 merged: xz = x @ Win -> xc (buf1) + z (zbuf), one dispatch, 2048 blocks
    gemm_in2<<<dim3(2 * D_INNER / 128, MROWS / 128), dim3(256), 0, stream>>>(x16, ipwT, buf1, zbuf);
    // K2: conv + silu -> xs
    conv_silu<<<dim3(MROWS * D_INNER / 256), dim3(256), 0, stream>>>(buf1, cw16, cb16, xs);
    // K3: proj via split-K MFMA + reduce (also emits proj_lo bf16)
    gemm_proj<<<dim3(KSPLIT, MROWS / 128), dim3(256), 0, stream>>>(xs, xpwT, Pp);
    reduce_proj<<<dim3(MROWS * PST / 256), dim3(256), 0, stream>>>(Pp, proj, proj_lo);
    // K4: dt via MFMA, fused bias+fast-softplus (dt16 overlays dead xc)
    gemm_dt<<<dim3(D_INNER / 128, MROWS / 128), dim3(256), 0, stream>>>(proj_lo, dtwT, dtb16, dt16);
    // K5: chunked scan
    scan_phase1<<<dim3(D_INNER / 256, NC, BATCH), dim3(256), 0, stream>>>(proj, dt16, Aws, xs, hloc, Ssum);
    scan_phase2<<<dim3(BATCH * D_INNER * D_STATE / 256), dim3(256), 0, stream>>>(Aws, Ssum, hloc);
    scan_phase3<<<dim3(D_INNER / 256, NC, BATCH), dim3(256), 0, stream>>>(proj, dt16, Aws, D16, hloc, zbuf, xs);
    // K6: out = y @ out_proj_w   (sw=1: grid x=m for per-XCD L2 locality)
    gemm_bt<<<dim3(MROWS / 128, D_MODEL / 128), dim3(256), 0, stream>>>(
        xs, opwT, D_INNER, d_out, D_MODEL, 1, 1, flag);
}

// Round 9
// 550.259 us; speedup vs baseline: 1.2329x; 1.0290x over previous
//
#include <hip/hip_runtime.h>
#include <hip/hip_bf16.h>

// Problem constants
#define D_MODEL 1024
#define D_INNER 4096
#define D_STATE 16
#define D_CONV 4
#define DT_RANK 64
#define BATCH 2
#define SEQLEN 2048
#define MROWS (BATCH * SEQLEN)          // 4096
#define NPROJ (DT_RANK + 2 * D_STATE)   // 96
#define PST 128                         // proj row stride (padded, fp32)
#define NC 32                           // scan chunks
#define TC (SEQLEN / NC)                // 64 steps per chunk
#define KSPLIT 8                        // split-K for proj gemm
#define KSP6 4                          // split-K for out gemm

typedef unsigned short u16;
typedef unsigned int u32;
typedef __attribute__((ext_vector_type(8))) short short8;
typedef __attribute__((ext_vector_type(4))) float floatx4;

__device__ __forceinline__ float bf2f(u16 u) {
    union { u32 i; float f; } v; v.i = ((u32)u) << 16; return v.f;
}
__device__ __forceinline__ u16 f2bf(float f) {
    union { float f; u32 i; } v; v.f = f;
    u32 x = v.i;
    u32 r = x + 0x7fffu + ((x >> 16) & 1u);   // round to nearest even
    return (u16)(r >> 16);
}
// fast softplus: hardware exp/log; |err| << bf16 ulp for all finite x
__device__ __forceinline__ float softplus_fast(float x) {
    float l = __logf(1.f + __expf(-fabsf(x)));
    return x > 0.f ? x + l : l;
}
// async global->LDS 16B DMA (dest = wave-uniform base + lane*16)
__device__ __forceinline__ void async_cp16(const u16* g, u16* l) {
    __builtin_amdgcn_global_load_lds((const __attribute__((address_space(1))) void*)g,
                                     (__attribute__((address_space(3))) void*)l, 16, 0, 0);
}

// ---------------------------------------------------------------------------
// D0: detect input dtype (bf16 vs fp32) from exponent-field statistics.
__global__ __launch_bounds__(256) void detect_dtype(const u16* __restrict__ x, int* __restrict__ flag) {
    __shared__ int cnt;
    if (threadIdx.x == 0) cnt = 0;
    __syncthreads();
    int local = 0;
    for (int k = 0; k < 16; k++) {
        int e = threadIdx.x * 8192 + k * 512;
        u16 v = x[2 * e];
        int ex = (v >> 7) & 0xFF;
        if (ex >= 0x68 && ex <= 0x8F) local++;
    }
    atomicAdd(&cnt, local);
    __syncthreads();
    if (threadIdx.x == 0) *flag = (cnt >= 2458) ? 1 : 0;
}

// ---------------------------------------------------------------------------
__global__ __launch_bounds__(256) void ingest16(const void* __restrict__ src, u16* __restrict__ dst,
                                                int n, const int* __restrict__ flag) {
    int i = blockIdx.x * 256 + threadIdx.x;
    if (i >= n) return;
    if (*flag) dst[i] = ((const u16*)src)[i];
    else       dst[i] = f2bf(((const float*)src)[i]);
}

// ---------------------------------------------------------------------------
// Fused small-tensor prologue: conv_w, conv_b, dt_proj_b, D ingest + A=-exp(A_log).
__global__ __launch_bounds__(256) void prep_small(const void* __restrict__ cw, const void* __restrict__ cb,
                                                  const void* __restrict__ dtb, const void* __restrict__ Dv,
                                                  const void* __restrict__ Alog,
                                                  u16* __restrict__ cw16, u16* __restrict__ cb16,
                                                  u16* __restrict__ dtb16, u16* __restrict__ D16,
                                                  float* __restrict__ A, const int* __restrict__ flag) {
    int i = blockIdx.x * 256 + threadIdx.x;   // grid covers 65536
    int isb = *flag;
    if (i < D_INNER * D_CONV)
        cw16[i] = isb ? ((const u16*)cw)[i] : f2bf(((const float*)cw)[i]);
    if (i < D_INNER) {
        cb16[i]  = isb ? ((const u16*)cb)[i]  : f2bf(((const float*)cb)[i]);
        dtb16[i] = isb ? ((const u16*)dtb)[i] : f2bf(((const float*)dtb)[i]);
        D16[i]   = isb ? ((const u16*)Dv)[i]  : f2bf(((const float*)Dv)[i]);
    }
    if (i < D_INNER * D_STATE) {
        float v = isb ? bf2f(((const u16*)Alog)[i]) : ((const float*)Alog)[i];
        A[i] = -expf(v);
    }
}

// ---------------------------------------------------------------------------
// Transpose-ingest: W [K][N] (dual dtype) -> WT [N][K] bf16.
__global__ __launch_bounds__(256) void transpose_w(const void* __restrict__ W, u16* __restrict__ WT,
                                                   int K, int N, const int* __restrict__ flag) {
    __shared__ float t[32][33];
    int k0 = blockIdx.y * 32, n0 = blockIdx.x * 32;
    int tid = threadIdx.x;
    int r = tid >> 3, c4 = (tid & 7) * 4;
    int isb = *flag;
    size_t base = (size_t)(k0 + r) * N + n0 + c4;
    float4 v;
    if (isb) { ushort4 u4 = *(const ushort4*)((const u16*)W + base);
               v = make_float4(bf2f(u4.x), bf2f(u4.y), bf2f(u4.z), bf2f(u4.w)); }
    else     { v = *(const float4*)((const float*)W + base); }
    t[c4 + 0][r] = v.x; t[c4 + 1][r] = v.y; t[c4 + 2][r] = v.z; t[c4 + 3][r] = v.w;
    __syncthreads();
    u16* o = WT + (size_t)(n0 + r) * K + k0 + c4;
    o[0] = f2bf(t[r][c4 + 0]);
    o[1] = f2bf(t[r][c4 + 1]);
    o[2] = f2bf(t[r][c4 + 2]);
    o[3] = f2bf(t[r][c4 + 3]);
}

// ---------------------------------------------------------------------------
// K1 merged: xz = x @ in_proj_w, N=8192.  1D grid (2048), XCD-swizzled:
// bid&7 selects an 8-n-tile panel group so each XCD's L2 keeps its B-panel.
__global__ __launch_bounds__(256) void gemm_in2(const u16* __restrict__ A, const u16* __restrict__ Bt,
                                                u16* __restrict__ xc, u16* __restrict__ z) {
    const int K = D_MODEL;
    __shared__ __align__(16) u16 sA[128 * 32];
    __shared__ __align__(16) u16 sB[128 * 32];
    int tid = threadIdx.x;
    int lane = tid & 63;
    int wave = tid >> 6;
    int wm = (wave >> 1) * 64, wn = (wave & 1) * 64;
    int quad = lane >> 4, l15 = lane & 15;
    int bid = blockIdx.x;
    int xcd = bid & 7;
    int idx = bid >> 3;                 // 0..255
    int nt = xcd * 8 + (idx & 7);       // 64 n-tiles, 8 per XCD group
    int mt = idx >> 3;                  // 32 m-tiles
    int m0 = mt * 128, n0 = nt * 128;

    floatx4 acc[4][4];
#pragma unroll
    for (int i = 0; i < 4; i++)
#pragma unroll
        for (int j = 0; j < 4; j++) acc[i][j] = (floatx4)0.f;

    const u16* ga0 = A + (size_t)(m0 + (tid >> 2)) * K + (tid & 3) * 8;
    const u16* ga1 = A + (size_t)(m0 + 64 + (tid >> 2)) * K + (tid & 3) * 8;
    const u16* gb0 = Bt + (size_t)(n0 + (tid >> 2)) * K + (tid & 3) * 8;
    const u16* gb1 = Bt + (size_t)(n0 + 64 + (tid >> 2)) * K + (tid & 3) * 8;
    u16* la0 = &sA[tid * 8];
    u16* la1 = &sA[(256 + tid) * 8];
    u16* lb0 = &sB[tid * 8];
    u16* lb1 = &sB[(256 + tid) * 8];

    for (int k0 = 0; k0 < K; k0 += 32) {
        async_cp16(ga0 + k0, la0);
        async_cp16(ga1 + k0, la1);
        async_cp16(gb0 + k0, lb0);
        async_cp16(gb1 + k0, lb1);
        __syncthreads();
        short8 af[4], bf[4];
#pragma unroll
        for (int i = 0; i < 4; i++) {
            af[i] = *(const short8*)&sA[(wm + i * 16 + l15) * 32 + quad * 8];
            bf[i] = *(const short8*)&sB[(wn + i * 16 + l15) * 32 + quad * 8];
        }
#pragma unroll
        for (int i = 0; i < 4; i++)
#pragma unroll
            for (int j = 0; j < 4; j++)
                acc[i][j] = __builtin_amdgcn_mfma_f32_16x16x32_bf16(af[i], bf[j], acc[i][j], 0, 0, 0);
        __syncthreads();
    }

    u16* d = (n0 < D_INNER) ? xc : z;
    int nb = (n0 < D_INNER) ? n0 : n0 - D_INNER;
#pragma unroll
    for (int i = 0; i < 4; i++)
#pragma unroll
        for (int j = 0; j < 4; j++)
#pragma unroll
            for (int r = 0; r < 4; r++) {
                int mm = m0 + wm + i * 16 + quad * 4 + r;
                int nn = nb + wn + j * 16 + l15;
                d[(size_t)mm * D_INNER + nn] = f2bf(acc[i][j][r]);
            }
}

// ---------------------------------------------------------------------------
// K6 split-K: out partials = y[4096,4096] @ opwT[1024,4096]^T over K/4 slices.
// grid (N/128=8, M/128=32, KSP6=4) = 1024 blocks (4/CU).
__global__ __launch_bounds__(256) void gemm_out_sk(const u16* __restrict__ A, const u16* __restrict__ Bt,
                                                   float* __restrict__ Pp) {
    const int K = D_INNER;
    __shared__ __align__(16) u16 sA[128 * 32];
    __shared__ __align__(16) u16 sB[128 * 32];
    int tid = threadIdx.x;
    int lane = tid & 63;
    int wave = tid >> 6;
    int wm = (wave >> 1) * 64, wn = (wave & 1) * 64;
    int quad = lane >> 4, l15 = lane & 15;
    int m0 = blockIdx.y * 128, n0 = blockIdx.x * 128;
    int kz = blockIdx.z;
    int kbase = kz * (K / KSP6);

    floatx4 acc[4][4];
#pragma unroll
    for (int i = 0; i < 4; i++)
#pragma unroll
        for (int j = 0; j < 4; j++) acc[i][j] = (floatx4)0.f;

    const u16* ga0 = A + (size_t)(m0 + (tid >> 2)) * K + (tid & 3) * 8;
    const u16* ga1 = A + (size_t)(m0 + 64 + (tid >> 2)) * K + (tid & 3) * 8;
    const u16* gb0 = Bt + (size_t)(n0 + (tid >> 2)) * K + (tid & 3) * 8;
    const u16* gb1 = Bt + (size_t)(n0 + 64 + (tid >> 2)) * K + (tid & 3) * 8;
    u16* la0 = &sA[tid * 8];
    u16* la1 = &sA[(256 + tid) * 8];
    u16* lb0 = &sB[tid * 8];
    u16* lb1 = &sB[(256 + tid) * 8];

    for (int k0 = kbase; k0 < kbase + K / KSP6; k0 += 32) {
        async_cp16(ga0 + k0, la0);
        async_cp16(ga1 + k0, la1);
        async_cp16(gb0 + k0, lb0);
        async_cp16(gb1 + k0, lb1);
        __syncthreads();
        short8 af[4], bf[4];
#pragma unroll
        for (int i = 0; i < 4; i++) {
            af[i] = *(const short8*)&sA[(wm + i * 16 + l15) * 32 + quad * 8];
            bf[i] = *(const short8*)&sB[(wn + i * 16 + l15) * 32 + quad * 8];
        }
#pragma unroll
        for (int i = 0; i < 4; i++)
#pragma unroll
            for (int j = 0; j < 4; j++)
                acc[i][j] = __builtin_amdgcn_mfma_f32_16x16x32_bf16(af[i], bf[j], acc[i][j], 0, 0, 0);
        __syncthreads();
    }

    float* d = Pp + (size_t)kz * MROWS * D_MODEL;
#pragma unroll
    for (int i = 0; i < 4; i++)
#pragma unroll
        for (int j = 0; j < 4; j++)
#pragma unroll
            for (int r = 0; r < 4; r++) {
                int mm = m0 + wm + i * 16 + quad * 4 + r;
                int nn = n0 + wn + j * 16 + l15;
                d[(size_t)mm * D_MODEL + nn] = acc[i][j][r];
            }
}

// ---------------------------------------------------------------------------
__global__ __launch_bounds__(256) void reduce_out(const float* __restrict__ Pp, void* __restrict__ out,
                                                  const int* __restrict__ flag) {
    int i = blockIdx.x * 256 + threadIdx.x;   // < MROWS*D_MODEL
    float s = 0.f;
#pragma unroll
    for (int z = 0; z < KSP6; z++) s += Pp[(size_t)z * MROWS * D_MODEL + i];
    if (*flag) ((u16*)out)[i] = f2bf(s);
    else       ((float*)out)[i] = s;
}

// ---------------------------------------------------------------------------
// K3: proj split-K MFMA.  A = xs [4096][4096], Bt = xpwT [128(pad)][4096].
__global__ __launch_bounds__(256) void gemm_proj(const u16* __restrict__ A, const u16* __restrict__ Bt,
                                                 float* __restrict__ Pp) {
    const int K = D_INNER;
    __shared__ __align__(16) u16 sA[128 * 32];
    __shared__ __align__(16) u16 sB[128 * 32];
    int tid = threadIdx.x;
    int lane = tid & 63;
    int wave = tid >> 6;
    int wm = (wave >> 1) * 64, wn = (wave & 1) * 64;
    int quad = lane >> 4, l15 = lane & 15;
    int m0 = blockIdx.y * 128;
    int kz = blockIdx.x;
    int kbase = kz * (K / KSPLIT);

    floatx4 acc[4][4];
#pragma unroll
    for (int i = 0; i < 4; i++)
#pragma unroll
        for (int j = 0; j < 4; j++) acc[i][j] = (floatx4)0.f;

    const u16* ga0 = A + (size_t)(m0 + (tid >> 2)) * K + (tid & 3) * 8;
    const u16* ga1 = A + (size_t)(m0 + 64 + (tid >> 2)) * K + (tid & 3) * 8;
    const u16* gb0 = Bt + (size_t)(tid >> 2) * K + (tid & 3) * 8;
    const u16* gb1 = Bt + (size_t)(64 + (tid >> 2)) * K + (tid & 3) * 8;
    u16* la0 = &sA[tid * 8];
    u16* la1 = &sA[(256 + tid) * 8];
    u16* lb0 = &sB[tid * 8];
    u16* lb1 = &sB[(256 + tid) * 8];

    for (int k0 = kbase; k0 < kbase + K / KSPLIT; k0 += 32) {
        async_cp16(ga0 + k0, la0);
        async_cp16(ga1 + k0, la1);
        async_cp16(gb0 + k0, lb0);
        async_cp16(gb1 + k0, lb1);
        __syncthreads();
        short8 af[4], bf[4];
#pragma unroll
        for (int i = 0; i < 4; i++) {
            af[i] = *(const short8*)&sA[(wm + i * 16 + l15) * 32 + quad * 8];
            bf[i] = *(const short8*)&sB[(wn + i * 16 + l15) * 32 + quad * 8];
        }
#pragma unroll
        for (int i = 0; i < 4; i++)
#pragma unroll
            for (int j = 0; j < 4; j++)
                acc[i][j] = __builtin_amdgcn_mfma_f32_16x16x32_bf16(af[i], bf[j], acc[i][j], 0, 0, 0);
        __syncthreads();
    }

    float* d = Pp + (size_t)kz * MROWS * PST;
#pragma unroll
    for (int i = 0; i < 4; i++)
#pragma unroll
        for (int j = 0; j < 4; j++)
#pragma unroll
            for (int r = 0; r < 4; r++) {
                int mm = m0 + wm + i * 16 + quad * 4 + r;
                int nn = wn + j * 16 + l15;
                d[(size_t)mm * PST + nn] = acc[i][j][r];
            }
}

// ---------------------------------------------------------------------------
// reduce split-K partials -> proj fp32 [4096][PST]; also emit proj_lo bf16.
__global__ __launch_bounds__(256) void reduce_proj(const float* __restrict__ Pp, float* __restrict__ proj,
                                                   u16* __restrict__ proj_lo) {
    int i = blockIdx.x * 256 + threadIdx.x;    // < MROWS*PST
    float s = 0.f;
#pragma unroll
    for (int z = 0; z < KSPLIT; z++) s += Pp[(size_t)z * MROWS * PST + i];
    proj[i] = s;
    int col = i & (PST - 1);
    if (col < DT_RANK) proj_lo[(size_t)(i >> 7) * DT_RANK + col] = f2bf(s);
}

// ---------------------------------------------------------------------------
// K4: dt = softplus(proj_lo @ dtwT^T + b) via MFMA.  M=4096, N=4096, K=64.
// Epilogue: fast softplus + LDS bounce (stride-132 pad) -> coalesced 16B stores.
__global__ __launch_bounds__(256) void gemm_dt(const u16* __restrict__ A, const u16* __restrict__ Bt,
                                               const u16* __restrict__ dtb, u16* __restrict__ dt) {
    const int K = DT_RANK;   // 64
    __shared__ __align__(16) u16 smem[64 * 132];   // 16.9 KB; k-loop uses first 16 KB
    u16* sA = smem;
    u16* sB = smem + 128 * 32;
    int tid = threadIdx.x;
    int lane = tid & 63;
    int wave = tid >> 6;
    int wm = (wave >> 1) * 64, wn = (wave & 1) * 64;
    int quad = lane >> 4, l15 = lane & 15;
    int m0 = blockIdx.y * 128, n0 = blockIdx.x * 128;

    floatx4 acc[4][4];
#pragma unroll
    for (int i = 0; i < 4; i++)
#pragma unroll
        for (int j = 0; j < 4; j++) acc[i][j] = (floatx4)0.f;

    const u16* ga0 = A + (size_t)(m0 + (tid >> 2)) * K + (tid & 3) * 8;
    const u16* ga1 = A + (size_t)(m0 + 64 + (tid >> 2)) * K + (tid & 3) * 8;
    const u16* gb0 = Bt + (size_t)(n0 + (tid >> 2)) * K + (tid & 3) * 8;
    const u16* gb1 = Bt + (size_t)(n0 + 64 + (tid >> 2)) * K + (tid & 3) * 8;
    u16* la0 = &sA[tid * 8];
    u16* la1 = &sA[(256 + tid) * 8];
    u16* lb0 = &sB[tid * 8];
    u16* lb1 = &sB[(256 + tid) * 8];

    for (int k0 = 0; k0 < K; k0 += 32) {
        async_cp16(ga0 + k0, la0);
        async_cp16(ga1 + k0, la1);
        async_cp16(gb0 + k0, lb0);
        async_cp16(gb1 + k0, lb1);
        __syncthreads();
        short8 af[4], bf[4];
#pragma unroll
        for (int i = 0; i < 4; i++) {
            af[i] = *(const short8*)&sA[(wm + i * 16 + l15) * 32 + quad * 8];
            bf[i] = *(const short8*)&sB[(wn + i * 16 + l15) * 32 + quad * 8];
        }
#pragma unroll
        for (int i = 0; i < 4; i++)
#pragma unroll
            for (int j = 0; j < 4; j++)
                acc[i][j] = __builtin_amdgcn_mfma_f32_16x16x32_bf16(af[i], bf[j], acc[i][j], 0, 0, 0);
        __syncthreads();
    }

#pragma unroll
    for (int h = 0; h < 2; h++) {
        __syncthreads();
        if (wm == h * 64) {
#pragma unroll
            for (int j = 0; j < 4; j++) {
                int col = wn + j * 16 + l15;
                float b = bf2f(dtb[n0 + col]);
#pragma unroll
                for (int i = 0; i < 4; i++)
#pragma unroll
                    for (int r = 0; r < 4; r++) {
                        int row = i * 16 + quad * 4 + r;   // 0..63 within half
                        smem[row * 132 + col] = f2bf(softplus_fast(acc[i][j][r] + b));
                    }
            }
        }
        __syncthreads();
#pragma unroll
        for (int p = 0; p < 4; p++) {
            int row = p * 16 + (tid >> 4);
            int chunk = tid & 15;
            uint4 v = *(const uint4*)&smem[row * 132 + chunk * 8];
            *(uint4*)&dt[(size_t)(m0 + h * 64 + row) * D_INNER + n0 + chunk * 8] = v;
        }
    }
}

// ---------------------------------------------------------------------------
// K2: causal depthwise conv1d + silu (bf16 in/out)
__global__ __launch_bounds__(256) void conv_silu(const u16* __restrict__ xc, const u16* __restrict__ cw,
                                                 const u16* __restrict__ cb, u16* __restrict__ xs) {
    int idx = blockIdx.x * 256 + threadIdx.x;
    int d = idx & (D_INNER - 1);
    int t = (idx >> 12) & (SEQLEN - 1);
    int b = idx >> 23;
    float w0 = bf2f(cw[d * 4 + 0]), w1 = bf2f(cw[d * 4 + 1]);
    float w2 = bf2f(cw[d * 4 + 2]), w3 = bf2f(cw[d * 4 + 3]);
    float acc = bf2f(cb[d]);
    size_t base = (size_t)b * SEQLEN * D_INNER + d;
    if (t >= 3) acc += bf2f(xc[base + (size_t)(t - 3) * D_INNER]) * w0;
    if (t >= 2) acc += bf2f(xc[base + (size_t)(t - 2) * D_INNER]) * w1;
    if (t >= 1) acc += bf2f(xc[base + (size_t)(t - 1) * D_INNER]) * w2;
    acc += bf2f(xc[base + (size_t)t * D_INNER]) * w3;
    float s = acc / (1.f + expf(-acc));
    xs[idx] = f2bf(s);
}

// ---------------------------------------------------------------------------
// K5a: chunked scan phase 1 — per (b,d,chunk) thread, 16 states in registers.
__global__ __launch_bounds__(256) void scan_phase1(const float* __restrict__ proj, const u16* __restrict__ dt,
                                                   const float* __restrict__ A, const u16* __restrict__ xs,
                                                   float* __restrict__ hloc, float* __restrict__ Ssum) {
    __shared__ float Bsh[TC][16];
    int d = blockIdx.x * 256 + threadIdx.x;
    int c = blockIdx.y, b = blockIdx.z;
    int t0 = c * TC;
    {
        int i = threadIdx.x >> 2;
        int q = threadIdx.x & 3;
        const float* src = proj + ((size_t)b * SEQLEN + t0 + i) * PST + DT_RANK + q * 4;
        *(float4*)&Bsh[i][q * 4] = *(const float4*)src;
    }
    __syncthreads();
    float Areg[16];
#pragma unroll
    for (int n = 0; n < 16; n++) Areg[n] = A[d * 16 + n];
    float h[16];
#pragma unroll
    for (int n = 0; n < 16; n++) h[n] = 0.f;
    float S = 0.f;
    size_t base = ((size_t)b * SEQLEN + t0) * D_INNER + d;
    for (int t = 0; t < TC; t++) {
        size_t idx = base + (size_t)t * D_INNER;
        float dtv = bf2f(dt[idx]);
        float u = bf2f(xs[idx]);
        S += dtv;
        float du = dtv * u;
#pragma unroll
        for (int n = 0; n < 16; n++) {
            h[n] = h[n] * __expf(dtv * Areg[n]) + du * Bsh[t][n];
        }
    }
    float* hp = &hloc[(((size_t)b * NC + c) * D_INNER + d) * 16];
#pragma unroll
    for (int n = 0; n < 16; n += 4)
        *(float4*)&hp[n] = make_float4(h[n], h[n + 1], h[n + 2], h[n + 3]);
    Ssum[((size_t)b * NC + c) * D_INNER + d] = S;
}

// ---------------------------------------------------------------------------
// K5b: combine chunks serially (in place: hloc becomes h_init per chunk).
__global__ __launch_bounds__(256) void scan_phase2(const float* __restrict__ A, const float* __restrict__ Ssum,
                                                   float* __restrict__ hloc) {
    int tid = blockIdx.x * 256 + threadIdx.x;
    int n = tid & 15;
    int d = (tid >> 4) & (D_INNER - 1);
    int b = tid >> 16;
    float An = A[d * 16 + n];
    float h = 0.f;
    for (int c = 0; c < NC; c++) {
        size_t idx = (((size_t)b * NC + c) * D_INNER + d) * 16 + n;
        float hl = hloc[idx];
        float S = Ssum[((size_t)b * NC + c) * D_INNER + d];
        hloc[idx] = h;
        h = hl + h * __expf(An * S);
    }
}

// ---------------------------------------------------------------------------
// K5c: phase 3 — rerun chunk with h_init, compute y, D-residual, silu(z) gate.
__global__ __launch_bounds__(256) void scan_phase3(const float* __restrict__ proj, const u16* __restrict__ dt,
                                                   const float* __restrict__ A, const u16* __restrict__ D16,
                                                   const float* __restrict__ hinit, const u16* __restrict__ z16,
                                                   u16* __restrict__ xs) {
    __shared__ float BC[TC][32];
    int d = blockIdx.x * 256 + threadIdx.x;
    int c = blockIdx.y, b = blockIdx.z;
    int t0 = c * TC;
    {
        int i = threadIdx.x >> 2;
        int q = threadIdx.x & 3;
        const float* src = proj + ((size_t)b * SEQLEN + t0 + i) * PST + DT_RANK + q * 8;
        *(float4*)&BC[i][q * 8 + 0] = *(const float4*)(src + 0);
        *(float4*)&BC[i][q * 8 + 4] = *(const float4*)(src + 4);
    }
    __syncthreads();
    float Areg[16];
#pragma unroll
    for (int n = 0; n < 16; n++) Areg[n] = A[d * 16 + n];
    float h[16];
    {
        const float* hp = &hinit[(((size_t)b * NC + c) * D_INNER + d) * 16];
#pragma unroll
        for (int n = 0; n < 16; n += 4) {
            float4 v = *(const float4*)&hp[n];
            h[n] = v.x; h[n + 1] = v.y; h[n + 2] = v.z; h[n + 3] = v.w;
        }
    }
    float Dd = bf2f(D16[d]);
    size_t base = ((size_t)b * SEQLEN + t0) * D_INNER + d;
    for (int t = 0; t < TC; t++) {
        size_t idx = base + (size_t)t * D_INNER;
        float dtv = bf2f(dt[idx]);
        float u = bf2f(xs[idx]);
        float zv = bf2f(z16[idx]);
        float du = dtv * u;
        float y = 0.f;
#pragma unroll
        for (int n = 0; n < 16; n++) {
            h[n] = h[n] * __expf(dtv * Areg[n]) + du * BC[t][n];
            y += h[n] * BC[t][16 + n];
        }
        float gate = zv / (1.f + __expf(-zv));
        xs[idx] = f2bf((y + u * Dd) * gate);
    }
}

// ---------------------------------------------------------------------------
extern "C" void kernel_launch(void* const* d_in, const int* in_sizes, int n_in,
                              void* d_out, int out_size, void* d_ws, size_t ws_size,
                              hipStream_t stream) {
    const void* x          = d_in[0];
    const void* in_proj_w  = d_in[1];
    const void* conv_w     = d_in[2];
    const void* conv_b     = d_in[3];
    const void* x_proj_w   = d_in[4];
    const void* dt_proj_w  = d_in[5];
    const void* dt_proj_b  = d_in[6];
    const void* A_log      = d_in[7];
    const void* Dvec       = d_in[8];
    const void* out_proj_w = d_in[9];

    char* w = (char*)d_ws;
    const size_t MB = 1024 * 1024;
    const size_t KB = 1024;
    // Overlay plan (stream order guarantees safety):
    //   5-37 MB  : xc (K1 out, dead after conv) -> dt16 -> Pp6 lower half
    //  37-69 MB  : z (dead after scan_phase3)   -> Pp6 upper half
    //  69-101 MB : xs (conv out) -> gated y (K6 A operand)
    // 101-126 MB : x16+ipwT (dead after K1) -> Pp (dead after reduce) -> hloc
    int*   flag    = (int*)(w + 0);
    float* Aws     = (float*)(w + 1 * KB);          // 256 KB
    float* proj    = (float*)(w + 1 * MB);          // 2 MB fp32 [4096][PST=128]
    u16*   cw16    = (u16*)(w + 3 * MB);            // 32 KB
    u16*   cb16    = (u16*)(w + 3 * MB + 64 * KB);  // 8 KB
    u16*   dtb16   = (u16*)(w + 3 * MB + 128 * KB); // 8 KB
    u16*   D16     = (u16*)(w + 3 * MB + 192 * KB); // 8 KB
    u16*   proj_lo = (u16*)(w + 3 * MB + 512 * KB); // 512 KB bf16 [4096][64]
    u16*   dtwT    = (u16*)(w + 4 * MB);            // 512 KB bf16 [4096][64]
    u16*   buf1    = (u16*)(w + 5 * MB);            // 32 MB: xc then dt16
    u16*   dt16    = buf1;
    u16*   zbuf    = (u16*)(w + 37 * MB);           // 32 MB: z
    float* Pp6     = (float*)(w + 5 * MB);          // 64 MB: K6 partials (post-scan)
    u16*   xs      = (u16*)(w + 69 * MB);           // 32 MB: xs then gated y
    u16*   x16     = (u16*)(w + 101 * MB);          // 8.4 MB  (dead after K1)
    u16*   ipwT    = (u16*)(w + 110 * MB);          // 16.8 MB (dead after K1)
    float* Pp      = (float*)(w + 101 * MB);        // 16 MB (post-K1, dead after reduce)
    float* hloc    = (float*)(w + 101 * MB);        // 16 MB (post-reduce)
    float* Ssum    = (float*)(w + 117 * MB);        // 1 MB  (post-K1)
    u16*   opwT    = (u16*)(w + 127 * MB);          // 8.4 MB: out_proj_w^T [1024][4096]
    u16*   xpwT    = (u16*)(w + 136 * MB);          // 1 MB: x_proj_w^T [96(pad128)][4096]
    // total 137 MB (<150 MB proven available)

    detect_dtype<<<dim3(1), dim3(256), 0, stream>>>((const u16*)x, flag);
    prep_small<<<dim3(256), dim3(256), 0, stream>>>(conv_w, conv_b, dt_proj_b, Dvec, A_log,
                                                    cw16, cb16, dtb16, D16, Aws, flag);
    ingest16<<<dim3(MROWS * D_MODEL / 256), dim3(256), 0, stream>>>(x, x16, MROWS * D_MODEL, flag);
    transpose_w<<<dim3(2 * D_INNER / 32, D_MODEL / 32), dim3(256), 0, stream>>>(in_proj_w, ipwT, D_MODEL, 2 * D_INNER, flag);
    transpose_w<<<dim3(D_MODEL / 32, D_INNER / 32), dim3(256), 0, stream>>>(out_proj_w, opwT, D_INNER, D_MODEL, flag);
    transpose_w<<<dim3(NPROJ / 32, D_INNER / 32), dim3(256), 0, stream>>>(x_proj_w, xpwT, D_INNER, NPROJ, flag);
    transpose_w<<<dim3(D_INNER / 32, DT_RANK / 32), dim3(256), 0, stream>>>(dt_proj_w, dtwT, DT_RANK, D_INNER, flag);

    // K1 merged: xz = x @ Win -> xc (buf1) + z (zbuf), 2048 blocks, XCD swizzle
    gemm_in2<<<dim3(2048), dim3(256), 0, stream>>>(x16, ipwT, buf1, zbuf);
    // K2: conv + silu -> xs
    conv_silu<<<dim3(MROWS * D_INNER / 256), dim3(256), 0, stream>>>(buf1, cw16, cb16, xs);
    // K3: proj via split-K MFMA + reduce (also emits proj_lo bf16)
    gemm_proj<<<dim3(KSPLIT, MROWS / 128), dim3(256), 0, stream>>>(xs, xpwT, Pp);
    reduce_proj<<<dim3(MROWS * PST / 256), dim3(256), 0, stream>>>(Pp, proj, proj_lo);
    // K4: dt via MFMA, fused bias+fast-softplus (dt16 overlays dead xc)
    gemm_dt<<<dim3(D_INNER / 128, MROWS / 128), dim3(256), 0, stream>>>(proj_lo, dtwT, dtb16, dt16);
    // K5: chunked scan
    scan_phase1<<<dim3(D_INNER / 256, NC, BATCH), dim3(256), 0, stream>>>(proj, dt16, Aws, xs, hloc, Ssum);
    scan_phase2<<<dim3(BATCH * D_INNER * D_STATE / 256), dim3(256), 0, stream>>>(Aws, Ssum, hloc);
    scan_phase3<<<dim3(D_INNER / 256, NC, BATCH), dim3(256), 0, stream>>>(proj, dt16, Aws, D16, hloc, zbuf, xs);
    // K6: out = y @ out_proj_w via split-K (dt16/zbuf dead -> Pp6) + reduce
    gemm_out_sk<<<dim3(D_MODEL / 128, MROWS / 128, KSP6), dim3(256), 0, stream>>>(xs, opwT, Pp6);
    reduce_out<<<dim3(MROWS * D_MODEL / 256), dim3(256), 0, stream>>>(Pp6, d_out, flag);
}